// Round 4
// baseline (757.495 us; speedup 1.0000x reference)
//
#include <hip/hip_runtime.h>
#include <hip/hip_bf16.h>
#include <math.h>

// LMU-FFT: x(32,4096,256), W_u(1,256), W_h(512,512), H(256,4096) -> h(32,4096,512), h_n(32,512)
//
// Round-4 structure (iFFT-then-GEMM, register-fused FFT ends, twiddle tables):
//   twiddles                   twiddle_kernel: (w,w2,w3) tables for R4 stages q=16..1024
//                              and R2 stage, fwd+inv, in ws (L2-resident, sincos-exact)
//   u = relu(x@W_u)            relu_u_kernel (also emits xh = fp16(x))
//   whfT = pack(W_h)           wh_pack_kernel (k-blocked fp16)
//   Uf, Hf = FFT(u), FFT(H)    fwd_all_kernel: R2 fused with zero-pad load (regs) ->
//                              LDS stages q=1024..16 (table twiddles) -> q=4,1 in regs
//                              -> store. (q=4/q=1 were 8-way bank conflicts in LDS.)
//   m = iFFT(Uf .* Hf-pairs)   conv_m_kernel: pointwise+q=1+q=4 in regs -> LDS stages
//                              q=16..1024 -> R2 fused with scale+fp16 pack (upper half
//                              never computed). 6 barriers/FFT, conflicted stages gone.
//   h = relu([m|x] @ W_h^T)    h_gemm_kernel: 128x128 tile, BK=64, global_load_lds(16B)
//                              staging, 2-barrier K-loop, fp16 MFMA (unchanged, verified).

#define BATCH 32
#define T     4096
#define IND   256
#define HID   512
#define MEM   256
#define FFT_N 8192
#define FFT_LOG 13
#define BT    131072   // BATCH*T

typedef __attribute__((ext_vector_type(8))) short short8;
typedef __attribute__((ext_vector_type(8))) _Float16 half8;
typedef __attribute__((ext_vector_type(4))) float f32x4;

__device__ inline short f2bf(float f) {
    unsigned u = __float_as_uint(f);
    unsigned r = (u + 0x7FFFu + ((u >> 16) & 1u)) >> 16;
    return (short)r;
}
__device__ inline unsigned pk2h(float a, float b) {
    union { _Float16 h[2]; unsigned u; } v;
    v.h[0] = (_Float16)a; v.h[1] = (_Float16)b;
    return v.u;
}
__device__ __forceinline__ void gl_lds16(const void* g, void* l) {
    __builtin_amdgcn_global_load_lds((const __attribute__((address_space(1))) unsigned*)g,
                                     (__attribute__((address_space(3))) unsigned*)l, 16, 0, 0);
}

// ============================ kernel 0: twiddle tables ============================
// t4*: 1360 entries x (w,w2,w3) for R4 stages: q=16 @0, q=64 @16, q=256 @80, q=1024 @336
// t2*: 4096 entries (w) for the R2 half=4096 stage. inv: +sn; fwd: -sn.
__global__ __launch_bounds__(512) void twiddle_kernel(float2* __restrict__ t4f,
                                                      float2* __restrict__ t2f,
                                                      float2* __restrict__ t4i,
                                                      float2* __restrict__ t2i) {
    int i = blockIdx.x * 512 + threadIdx.x;
    if (i < 4096) {
        float a = ((float)M_PI / 4096.f) * (float)i;
        float sn, cs; __sincosf(a, &sn, &cs);
        t2i[i] = make_float2(cs, sn);
        t2f[i] = make_float2(cs, -sn);
    } else if (i < 4096 + 1360) {
        int e = i - 4096;
        int q, j;
        if (e < 16)       { q = 16;   j = e; }
        else if (e < 80)  { q = 64;   j = e - 16; }
        else if (e < 336) { q = 256;  j = e - 80; }
        else              { q = 1024; j = e - 336; }
        float a = ((float)M_PI / (float)(2 * q)) * (float)j;
        float sn, cs; __sincosf(a, &sn, &cs);
        float w2r = cs * cs - sn * sn, w2i = 2.f * cs * sn;
        float w3r = w2r * cs - w2i * sn, w3i = w2r * sn + w2i * cs;
        t4i[e * 3 + 0] = make_float2(cs, sn);
        t4i[e * 3 + 1] = make_float2(w2r, w2i);
        t4i[e * 3 + 2] = make_float2(w3r, w3i);
        t4f[e * 3 + 0] = make_float2(cs, -sn);
        t4f[e * 3 + 1] = make_float2(w2r, -w2i);
        t4f[e * 3 + 2] = make_float2(w3r, -w3i);
    }
}

// ============================ kernel 1 ============================
__global__ __launch_bounds__(256) void relu_u_kernel(const float* __restrict__ x,
                                                     const float* __restrict__ Wu,
                                                     float* __restrict__ u,
                                                     _Float16* __restrict__ xh) {
    int wave = threadIdx.x >> 6, lane = threadIdx.x & 63;
    int r = blockIdx.x * 4 + wave;
    const float4 xv = *(const float4*)(x + (size_t)r * IND + lane * 4);
    const float4 wv = *(const float4*)(Wu + lane * 4);
    union { _Float16 h[4]; uint2 u2; } hv;
    hv.h[0] = (_Float16)xv.x; hv.h[1] = (_Float16)xv.y;
    hv.h[2] = (_Float16)xv.z; hv.h[3] = (_Float16)xv.w;
    *(uint2*)(xh + (size_t)r * IND + lane * 4) = hv.u2;
    float acc = xv.x * wv.x + xv.y * wv.y + xv.z * wv.z + xv.w * wv.w;
    for (int off = 32; off; off >>= 1) acc += __shfl_down(acc, off);
    if (lane == 0) u[r] = fmaxf(acc, 0.f);
}
__global__ __launch_bounds__(256) void relu_u_only_kernel(const float* __restrict__ x,
                                                          const float* __restrict__ Wu,
                                                          float* __restrict__ u) {
    int wave = threadIdx.x >> 6, lane = threadIdx.x & 63;
    int r = blockIdx.x * 4 + wave;
    const float4 xv = *(const float4*)(x + (size_t)r * IND + lane * 4);
    const float4 wv = *(const float4*)(Wu + lane * 4);
    float acc = xv.x * wv.x + xv.y * wv.y + xv.z * wv.z + xv.w * wv.w;
    for (int off = 32; off; off >>= 1) acc += __shfl_down(acc, off);
    if (lane == 0) u[r] = fmaxf(acc, 0.f);
}

// ============================ kernel 1b ============================
__global__ __launch_bounds__(256) void wh_pack_kernel(const float* __restrict__ Wh,
                                                      _Float16* __restrict__ whfT) {
    int i = blockIdx.x * 256 + threadIdx.x;
    int col = i >> 7;
    int kq  = (i & 127) << 2;
    float4 v = *(const float4*)(Wh + (size_t)col * HID + kq);
    _Float16* d = whfT + (size_t)(kq >> 3) * (HID * 8) + (size_t)col * 8 + (kq & 7);
    d[0] = (_Float16)v.x; d[1] = (_Float16)v.y;
    d[2] = (_Float16)v.z; d[3] = (_Float16)v.w;
}

// ============================ kernel 2: forward FFTs ============================
// blocks 0..31: u rows -> Uf; blocks 32..287: H rows -> Hf. Digit-reversed output.
__global__ __launch_bounds__(512) void fwd_all_kernel(const float* __restrict__ u,
                                                      const float* __restrict__ H,
                                                      const float2* __restrict__ t4f,
                                                      const float2* __restrict__ t2f,
                                                      float2* __restrict__ Uf,
                                                      float2* __restrict__ Hf) {
    __shared__ float re[FFT_N];
    __shared__ float im[FFT_N];
    int r = blockIdx.x;
    int n = threadIdx.x;
    const float* src = (r < BATCH) ? (u + (size_t)r * T) : (H + (size_t)(r - BATCH) * T);
    float2* dst = (r < BATCH) ? (Uf + (size_t)r * FFT_N) : (Hf + (size_t)(r - BATCH) * FFT_N);

    // ---- R2 stage (half=4096) fused with load + zero-pad: k = 8n..8n+7, upper input = 0
    {
        float4 s0 = *(const float4*)(src + 8 * n);
        float4 s1 = *(const float4*)(src + 8 * n + 4);
        float2 w8[8];
        *(float4*)&w8[0] = *(const float4*)(t2f + 8 * n);
        *(float4*)&w8[2] = *(const float4*)(t2f + 8 * n + 2);
        *(float4*)&w8[4] = *(const float4*)(t2f + 8 * n + 4);
        *(float4*)&w8[6] = *(const float4*)(t2f + 8 * n + 6);
        *(float4*)&re[8 * n]     = s0;
        *(float4*)&re[8 * n + 4] = s1;
        float4 z = make_float4(0.f, 0.f, 0.f, 0.f);
        *(float4*)&im[8 * n]     = z;
        *(float4*)&im[8 * n + 4] = z;
        float4 ru0 = make_float4(w8[0].x * s0.x, w8[1].x * s0.y, w8[2].x * s0.z, w8[3].x * s0.w);
        float4 ru1 = make_float4(w8[4].x * s1.x, w8[5].x * s1.y, w8[6].x * s1.z, w8[7].x * s1.w);
        float4 iu0 = make_float4(w8[0].y * s0.x, w8[1].y * s0.y, w8[2].y * s0.z, w8[3].y * s0.w);
        float4 iu1 = make_float4(w8[4].y * s1.x, w8[5].y * s1.y, w8[6].y * s1.z, w8[7].y * s1.w);
        *(float4*)&re[8 * n + 4096]     = ru0;
        *(float4*)&re[8 * n + 4096 + 4] = ru1;
        *(float4*)&im[8 * n + 4096]     = iu0;
        *(float4*)&im[8 * n + 4096 + 4] = iu1;
    }
    __syncthreads();
    // ---- R4 LDS stages q = 1024, 256, 64, 16 (DIF order, table twiddles)
#pragma unroll
    for (int st = 10; st >= 4; st -= 2) {
        int q = 1 << st;
        int toff = (st == 4) ? 0 : (st == 6) ? 16 : (st == 8) ? 80 : 336;
#pragma unroll
        for (int s = 0; s < 4; ++s) {
            int k = n + s * 512;
            int j = k & (q - 1);
            int i0 = ((k >> st) << (st + 2)) + j;
            const float2* tw = t4f + (size_t)(toff + j) * 3;
            float2 W1 = tw[0], W2 = tw[1], W3 = tw[2];
            float ar = re[i0],         ai = im[i0];
            float br = re[i0 + q],     bi = im[i0 + q];
            float cr = re[i0 + 2 * q], ci = im[i0 + 2 * q];
            float dr = re[i0 + 3 * q], di = im[i0 + 3 * q];
            float t0r = ar + cr, t0i = ai + ci;
            float t1r = ar - cr, t1i = ai - ci;
            float t2r = br + dr, t2i = bi + di;
            float t3r = bi - di, t3i = dr - br;
            re[i0] = t0r + t2r;               im[i0] = t0i + t2i;
            float er = t0r - t2r, ei = t0i - t2i;
            re[i0 + q] = er * W2.x - ei * W2.y;     im[i0 + q] = er * W2.y + ei * W2.x;
            float fr = t1r + t3r, fi = t1i + t3i;
            re[i0 + 2 * q] = fr * W1.x - fi * W1.y; im[i0 + 2 * q] = fr * W1.y + fi * W1.x;
            float gr = t1r - t3r, gi = t1i - t3i;
            re[i0 + 3 * q] = gr * W3.x - gi * W3.y; im[i0 + 3 * q] = gr * W3.y + gi * W3.x;
        }
        __syncthreads();
    }
    // ---- final q=4 and q=1 stages in registers (thread owns [16n,16n+16)), store
    {
        float pr[16], pi[16];
#pragma unroll
        for (int s4 = 0; s4 < 4; ++s4) {
            *(float4*)&pr[4 * s4] = *(float4*)&re[16 * n + 4 * s4];
            *(float4*)&pi[4 * s4] = *(float4*)&im[16 * n + 4 * s4];
        }
        // q=4 (fwd): j = 0..3, w = exp(-i pi j / 8)
#pragma unroll
        for (int j = 0; j < 4; ++j) {
            float sn, cs; __sincosf((-(float)M_PI / 8.f) * (float)j, &sn, &cs);
            float w2r = cs * cs - sn * sn, w2i = 2.f * cs * sn;
            float w3r = w2r * cs - w2i * sn, w3i = w2r * sn + w2i * cs;
            float ar = pr[j], ai = pi[j], br = pr[j + 4], bi = pi[j + 4];
            float cr = pr[j + 8], ci = pi[j + 8], dr = pr[j + 12], di = pi[j + 12];
            float t0r = ar + cr, t0i = ai + ci;
            float t1r = ar - cr, t1i = ai - ci;
            float t2r = br + dr, t2i = bi + di;
            float t3r = bi - di, t3i = dr - br;
            pr[j] = t0r + t2r; pi[j] = t0i + t2i;
            float er = t0r - t2r, ei = t0i - t2i;
            pr[j + 4] = er * w2r - ei * w2i;  pi[j + 4] = er * w2i + ei * w2r;
            float fr = t1r + t3r, fi = t1i + t3i;
            pr[j + 8] = fr * cs - fi * sn;    pi[j + 8] = fr * sn + fi * cs;
            float gr = t1r - t3r, gi = t1i - t3i;
            pr[j + 12] = gr * w3r - gi * w3i; pi[j + 12] = gr * w3i + gi * w3r;
        }
        // q=1 (twiddle-free)
#pragma unroll
        for (int g = 0; g < 4; ++g) {
            float ar = pr[4 * g], ai = pi[4 * g], br = pr[4 * g + 1], bi = pi[4 * g + 1];
            float cr = pr[4 * g + 2], ci = pi[4 * g + 2], dr = pr[4 * g + 3], di = pi[4 * g + 3];
            float t0r = ar + cr, t0i = ai + ci;
            float t1r = ar - cr, t1i = ai - ci;
            float t2r = br + dr, t2i = bi + di;
            float t3r = bi - di, t3i = dr - br;
            pr[4 * g]     = t0r + t2r; pi[4 * g]     = t0i + t2i;
            pr[4 * g + 1] = t0r - t2r; pi[4 * g + 1] = t0i - t2i;
            pr[4 * g + 2] = t1r + t3r; pi[4 * g + 2] = t1i + t3i;
            pr[4 * g + 3] = t1r - t3r; pi[4 * g + 3] = t1i - t3i;
        }
#pragma unroll
        for (int e = 0; e < 8; ++e) {
            float4 o = make_float4(pr[2 * e], pi[2 * e], pr[2 * e + 1], pi[2 * e + 1]);
            *(float4*)&dst[16 * n + 2 * e] = o;
        }
    }
}

// ============================ kernel 3: iFFT + pack ============================
// per (qblock, b): 4 iFFTs (8 q-channels). pointwise + q=1 + q=4 in registers,
// q=16..1024 via LDS (table twiddles), R2-last fused with scale + fp16 pack.
__global__ __launch_bounds__(512) void conv_m_kernel(const float2* __restrict__ Uf,
                                                     const float2* __restrict__ Hf,
                                                     const float2* __restrict__ t4i,
                                                     const float2* __restrict__ t2i,
                                                     _Float16* __restrict__ m2) {
    int qb = blockIdx.x;   // 0..31
    int b  = blockIdx.y;   // 0..31
    int n  = threadIdx.x;
    __shared__ float re[FFT_N];
    __shared__ float im[FFT_N];
    const float2* Ub = Uf + (size_t)b * FFT_N;
    const float inv = 1.0f / (float)FFT_N;
    unsigned pk0[8], pk1[8], pk2[8], pk3[8];

#define CONV_FF(FF, PK)                                                          \
    {                                                                            \
        const float2* Ha = Hf + (size_t)(qb * 8 + 2 * (FF)) * FFT_N;             \
        const float2* Hb = Ha + FFT_N;                                           \
        float pr[16], pi[16];                                                    \
        _Pragma("unroll")                                                        \
        for (int e = 0; e < 16; ++e) {                                           \
            int f = 16 * n + e;                                                  \
            float2 uv = Ub[f], h0 = Ha[f], h1 = Hb[f];                           \
            float gr = h0.x - h1.y, gi = h0.y + h1.x;                            \
            pr[e] = uv.x * gr - uv.y * gi;                                       \
            pi[e] = uv.x * gi + uv.y * gr;                                       \
        }                                                                        \
        _Pragma("unroll")  /* inv q=1, twiddle-free */                           \
        for (int g = 0; g < 4; ++g) {                                            \
            float Ar = pr[4*g], Ai = pi[4*g], Br = pr[4*g+1], Bi = pi[4*g+1];    \
            float Cr = pr[4*g+2], Ci = pi[4*g+2], Dr = pr[4*g+3], Di = pi[4*g+3];\
            float t0r = Ar+Br, t0i = Ai+Bi, t2r = Ar-Br, t2i = Ai-Bi;            \
            float t1r = Cr+Dr, t1i = Ci+Di, t3r = Cr-Dr, t3i = Ci-Di;            \
            pr[4*g]   = t0r+t1r; pi[4*g]   = t0i+t1i;                            \
            pr[4*g+2] = t0r-t1r; pi[4*g+2] = t0i-t1i;                            \
            pr[4*g+1] = t2r-t3i; pi[4*g+1] = t2i+t3r;                            \
            pr[4*g+3] = t2r+t3i; pi[4*g+3] = t2i-t3r;                            \
        }                                                                        \
        _Pragma("unroll")  /* inv q=4 */                                         \
        for (int j = 0; j < 4; ++j) {                                            \
            float sn, cs; __sincosf(((float)M_PI / 8.f) * (float)j, &sn, &cs);   \
            float w2r = cs*cs - sn*sn, w2i = 2.f*cs*sn;                          \
            float w3r = w2r*cs - w2i*sn, w3i = w2r*sn + w2i*cs;                  \
            float Ar = pr[j], Ai = pi[j], Br = pr[j+4], Bi = pi[j+4];            \
            float Cr = pr[j+8], Ci = pi[j+8], Dr = pr[j+12], Di = pi[j+12];      \
            float bpr = Br*w2r - Bi*w2i, bpi = Br*w2i + Bi*w2r;                  \
            float cpr = Cr*cs - Ci*sn,   cpi = Cr*sn + Ci*cs;                    \
            float dpr = Dr*w3r - Di*w3i, dpi = Dr*w3i + Di*w3r;                  \
            float t0r = Ar+bpr, t0i = Ai+bpi, t2r = Ar-bpr, t2i = Ai-bpi;        \
            float t1r = cpr+dpr, t1i = cpi+dpi, t3r = cpr-dpr, t3i = cpi-dpi;    \
            pr[j]    = t0r+t1r; pi[j]    = t0i+t1i;                              \
            pr[j+8]  = t0r-t1r; pi[j+8]  = t0i-t1i;                              \
            pr[j+4]  = t2r-t3i; pi[j+4]  = t2i+t3r;                              \
            pr[j+12] = t2r+t3i; pi[j+12] = t2i-t3r;                              \
        }                                                                        \
        if ((FF) > 0) __syncthreads();  /* prev FF's R2 reads done */            \
        _Pragma("unroll")                                                        \
        for (int s4 = 0; s4 < 4; ++s4) {                                         \
            *(float4*)&re[16*n + 4*s4] = *(float4*)&pr[4*s4];                    \
            *(float4*)&im[16*n + 4*s4] = *(float4*)&pi[4*s4];                    \
        }                                                                        \
        __syncthreads();                                                         \
        _Pragma("unroll")  /* LDS stages q=16,64,256,1024 */                     \
        for (int st = 4; st <= 10; st += 2) {                                    \
            int q = 1 << st;                                                     \
            int toff = (st == 4) ? 0 : (st == 6) ? 16 : (st == 8) ? 80 : 336;    \
            _Pragma("unroll")                                                    \
            for (int s = 0; s < 4; ++s) {                                        \
                int k = n + s * 512;                                             \
                int j = k & (q - 1);                                             \
                int i0 = ((k >> st) << (st + 2)) + j;                            \
                const float2* tw = t4i + (size_t)(toff + j) * 3;                 \
                float2 W1 = tw[0], W2 = tw[1], W3 = tw[2];                       \
                float Ar = re[i0],       Ai = im[i0];                            \
                float Br = re[i0+q],     Bi = im[i0+q];                          \
                float Cr = re[i0+2*q],   Ci = im[i0+2*q];                        \
                float Dr = re[i0+3*q],   Di = im[i0+3*q];                        \
                float bpr = Br*W2.x - Bi*W2.y, bpi = Br*W2.y + Bi*W2.x;          \
                float cpr = Cr*W1.x - Ci*W1.y, cpi = Cr*W1.y + Ci*W1.x;          \
                float dpr = Dr*W3.x - Di*W3.y, dpi = Dr*W3.y + Di*W3.x;          \
                float t0r = Ar+bpr, t0i = Ai+bpi, t2r = Ar-bpr, t2i = Ai-bpi;    \
                float t1r = cpr+dpr, t1i = cpi+dpi, t3r = cpr-dpr, t3i = cpi-dpi;\
                re[i0]       = t0r+t1r; im[i0]       = t0i+t1i;                  \
                re[i0+2*q]   = t0r-t1r; im[i0+2*q]   = t0i-t1i;                  \
                re[i0+q]     = t2r-t3i; im[i0+q]     = t2i+t3r;                  \
                re[i0+3*q]   = t2r+t3i; im[i0+3*q]   = t2i-t3r;                  \
            }                                                                    \
            __syncthreads();                                                     \
        }                                                                        \
        _Pragma("unroll")  /* R2-last fused + scale + pack (upper half unused) */\
        for (int s = 0; s < 8; ++s) {                                            \
            int k = n + 512 * s;                                                 \
            float2 W = t2i[k];                                                   \
            float br = re[k + 4096], bi = im[k + 4096];                          \
            float tr = W.x * br - W.y * bi, ti = W.x * bi + W.y * br;            \
            PK[s] = pk2h((re[k] + tr) * inv, (im[k] + ti) * inv);                \
        }                                                                        \
    }

    CONV_FF(0, pk0)
    CONV_FF(1, pk1)
    CONV_FF(2, pk2)
    CONV_FF(3, pk3)
#undef CONV_FF

    _Float16* dst = m2 + ((size_t)qb * BT + (size_t)b * T) * 8;
#pragma unroll
    for (int s = 0; s < 8; ++s) {
        int tt = n + 512 * s;
        uint4 w4;
        w4.x = pk0[s]; w4.y = pk1[s]; w4.z = pk2[s]; w4.w = pk3[s];
        *(uint4*)(dst + (size_t)tt * 8) = w4;
    }
}

// ============================ kernel 4: GEMM (unchanged, verified) ============================
__global__ __launch_bounds__(256) void h_gemm_kernel(const _Float16* __restrict__ xh,
                                                     const _Float16* __restrict__ whfT,
                                                     const _Float16* __restrict__ m2,
                                                     float* __restrict__ out) {
    __shared__ __align__(16) _Float16 As[8][128][8];
    __shared__ __align__(16) _Float16 Bs[8][128][8];
    int bn = blockIdx.x;
    int bm = blockIdx.y;
    int t = threadIdx.x;
    int wv = t >> 6, lane = t & 63;
    int wm = (wv & 1) * 64, wn = (wv >> 1) * 64;
    int ln = lane & 15, kg = lane >> 4;

    f32x4 acc[4][4] = {};
#pragma unroll
    for (int ks = 0; ks < 8; ++ks) {
        int kc = ks * 64;
        __syncthreads();
#pragma unroll
        for (int q = 0; q < 8; ++q) {
            int c = wv * 8 + q;
            int g = (c & 15) >> 1;
            int rg = c & 1;
            int row = rg * 64 + lane;
            if (c < 16) {
                const void* src;
                if (kc < MEM)
                    src = m2 + ((size_t)(kc / 8 + g) * BT + (size_t)bm * 128 + row) * 8;
                else
                    src = xh + (size_t)(bm * 128 + row) * IND + (kc - MEM) + g * 8;
                gl_lds16(src, &As[g][rg * 64][0]);
            } else {
                const void* src = whfT + (size_t)(kc / 8 + g) * (HID * 8)
                                       + (size_t)(bn * 128 + row) * 8;
                gl_lds16(src, &Bs[g][rg * 64][0]);
            }
        }
        __syncthreads();
        half8 af[2][4], bf[2][4];
#pragma unroll
        for (int kk = 0; kk < 2; ++kk) {
#pragma unroll
            for (int i = 0; i < 4; ++i)
                af[kk][i] = *(const half8*)&As[kk * 4 + kg][wm + i * 16 + ln][0];
#pragma unroll
            for (int j = 0; j < 4; ++j)
                bf[kk][j] = *(const half8*)&Bs[kk * 4 + kg][wn + j * 16 + ln][0];
        }
#pragma unroll
        for (int kk = 0; kk < 2; ++kk)
#pragma unroll
            for (int i = 0; i < 4; ++i)
#pragma unroll
                for (int j = 0; j < 4; ++j)
                    acc[i][j] = __builtin_amdgcn_mfma_f32_16x16x32_f16(af[kk][i], bf[kk][j],
                                                                       acc[i][j], 0, 0, 0);
    }
#pragma unroll
    for (int i = 0; i < 4; ++i) {
#pragma unroll
        for (int j = 0; j < 4; ++j) {
#pragma unroll
            for (int r = 0; r < 4; ++r) {
                int row = bm * 128 + wm + i * 16 + kg * 4 + r;
                int col = bn * 128 + wn + j * 16 + ln;
                float v = fmaxf(acc[i][j][r], 0.f);
                out[(size_t)row * HID + col] = v;
                if ((row & (T - 1)) == (T - 1))
                    out[(size_t)BATCH * T * HID + (size_t)(row >> 12) * HID + col] = v;
            }
        }
    }
}

// ================== OLD PATH (verbatim fallback, small ws) ==================
__device__ void fft_dif_fwd(float* re, float* im) {
    __syncthreads();
    for (int st = FFT_LOG; st >= 1; --st) {
        int half = 1 << (st - 1);
        float fm = -(float)M_PI / (float)half;
        for (int k = threadIdx.x; k < FFT_N / 2; k += 512) {
            int j  = k & (half - 1);
            int i1 = ((k >> (st - 1)) << st) + j;
            int i2 = i1 + half;
            float sn, cs;
            __sincosf(fm * (float)j, &sn, &cs);
            float ar = re[i1], ai = im[i1];
            float br = re[i2], bi = im[i2];
            re[i1] = ar + br; im[i1] = ai + bi;
            float dr = ar - br, di = ai - bi;
            re[i2] = cs * dr - sn * di;
            im[i2] = cs * di + sn * dr;
        }
        __syncthreads();
    }
}
__device__ void fft_dit_inv(float* re, float* im) {
    __syncthreads();
    for (int st = 1; st <= FFT_LOG; ++st) {
        int half = 1 << (st - 1);
        float fm = (float)M_PI / (float)half;
        for (int k = threadIdx.x; k < FFT_N / 2; k += 512) {
            int j  = k & (half - 1);
            int i1 = ((k >> (st - 1)) << st) + j;
            int i2 = i1 + half;
            float sn, cs;
            __sincosf(fm * (float)j, &sn, &cs);
            float br = re[i2], bi = im[i2];
            float tr = cs * br - sn * bi;
            float ti = cs * bi + sn * br;
            float ar = re[i1], ai = im[i1];
            re[i1] = ar + tr; im[i1] = ai + ti;
            re[i2] = ar - tr; im[i2] = ai - ti;
        }
        __syncthreads();
    }
}
__global__ __launch_bounds__(512) void fft_u_kernel(const float* __restrict__ u,
                                                    float2* __restrict__ Uf) {
    int b = blockIdx.x;
    __shared__ float re[FFT_N];
    __shared__ float im[FFT_N];
    for (int i = threadIdx.x; i < FFT_N; i += 512) {
        re[i] = i < T ? u[(size_t)b * T + i] : 0.f;
        im[i] = 0.f;
    }
    fft_dif_fwd(re, im);
    for (int i = threadIdx.x; i < FFT_N; i += 512)
        Uf[(size_t)b * FFT_N + i] = make_float2(re[i], im[i]);
}
__global__ __launch_bounds__(512) void g_fft_kernel(const float* __restrict__ Wh,
                                                    const float* __restrict__ H,
                                                    float2* __restrict__ Gf) {
    int o = blockIdx.x;
    __shared__ float re[FFT_N];
    __shared__ float im[FFT_N];
    const float* wrow = Wh + (size_t)o * HID;
    float acc[8];
#pragma unroll
    for (int d = 0; d < 8; ++d) acc[d] = 0.f;
    for (int q = 0; q < 256; ++q) {
        float w = wrow[q];
        const float* hrow = H + (size_t)q * T;
#pragma unroll
        for (int d = 0; d < 8; ++d)
            acc[d] = fmaf(w, hrow[threadIdx.x + d * 512], acc[d]);
    }
#pragma unroll
    for (int d = 0; d < 8; ++d) {
        re[threadIdx.x + d * 512] = acc[d];
        im[threadIdx.x + d * 512] = 0.f;
    }
    for (int i = T + threadIdx.x; i < FFT_N; i += 512) { re[i] = 0.f; im[i] = 0.f; }
    fft_dif_fwd(re, im);
    for (int i = threadIdx.x; i < FFT_N; i += 512)
        Gf[(size_t)o * FFT_N + i] = make_float2(re[i], im[i]);
}
__global__ __launch_bounds__(256) void xw_gemm_kernel(const float* __restrict__ x,
                                                      const float* __restrict__ Wh,
                                                      float* __restrict__ out) {
    __shared__ __align__(16) short Asl[4][128][8];
    __shared__ __align__(16) short Bsl[4][128][8];
    int bn = blockIdx.x;
    int bm = blockIdx.y;
    int t = threadIdx.x;
    int wv = t >> 6, lane = t & 63;
    int wm = (wv & 1) * 64, wn = (wv >> 1) * 64;
    int ln = lane & 15, kg = lane >> 4;
    f32x4 acc[4][4] = {};
    int mrow = t >> 1, khalf = t & 1;
    for (int kc = 0; kc < IND; kc += 32) {
        {
            const float* xr = x + ((size_t)(bm * 128 + mrow)) * IND + kc + khalf * 16;
            float4 v0 = *(const float4*)(xr + 0);
            float4 v1 = *(const float4*)(xr + 4);
            float4 v2 = *(const float4*)(xr + 8);
            float4 v3 = *(const float4*)(xr + 12);
            short8 s0 = { f2bf(v0.x), f2bf(v0.y), f2bf(v0.z), f2bf(v0.w),
                          f2bf(v1.x), f2bf(v1.y), f2bf(v1.z), f2bf(v1.w) };
            short8 s1 = { f2bf(v2.x), f2bf(v2.y), f2bf(v2.z), f2bf(v2.w),
                          f2bf(v3.x), f2bf(v3.y), f2bf(v3.z), f2bf(v3.w) };
            const float* wr = Wh + ((size_t)(bn * 128 + mrow)) * HID + 256 + kc + khalf * 16;
            float4 w0 = *(const float4*)(wr + 0);
            float4 w1 = *(const float4*)(wr + 4);
            float4 w2 = *(const float4*)(wr + 8);
            float4 w3 = *(const float4*)(wr + 12);
            short8 b0 = { f2bf(w0.x), f2bf(w0.y), f2bf(w0.z), f2bf(w0.w),
                          f2bf(w1.x), f2bf(w1.y), f2bf(w1.z), f2bf(w1.w) };
            short8 b1 = { f2bf(w2.x), f2bf(w2.y), f2bf(w2.z), f2bf(w2.w),
                          f2bf(w3.x), f2bf(w3.y), f2bf(w3.z), f2bf(w3.w) };
            __syncthreads();
            *(short8*)&Asl[khalf * 2 + 0][mrow][0] = s0;
            *(short8*)&Asl[khalf * 2 + 1][mrow][0] = s1;
            *(short8*)&Bsl[khalf * 2 + 0][mrow][0] = b0;
            *(short8*)&Bsl[khalf * 2 + 1][mrow][0] = b1;
            __syncthreads();
        }
        short8 af[4], bf[4];
#pragma unroll
        for (int i = 0; i < 4; ++i) af[i] = *(short8*)&Asl[kg][wm + i * 16 + ln][0];
#pragma unroll
        for (int j = 0; j < 4; ++j) bf[j] = *(short8*)&Bsl[kg][wn + j * 16 + ln][0];
#pragma unroll
        for (int i = 0; i < 4; ++i)
#pragma unroll
            for (int j = 0; j < 4; ++j)
                acc[i][j] = __builtin_amdgcn_mfma_f32_16x16x32_bf16(af[i], bf[j], acc[i][j], 0, 0, 0);
    }
#pragma unroll
    for (int i = 0; i < 4; ++i) {
#pragma unroll
        for (int j = 0; j < 4; ++j) {
#pragma unroll
            for (int r = 0; r < 4; ++r) {
                int row = bm * 128 + wm + i * 16 + (lane >> 4) * 4 + r;
                int col = bn * 128 + wn + j * 16 + (lane & 15);
                out[(size_t)row * HID + col] = acc[i][j][r];
            }
        }
    }
}
__global__ __launch_bounds__(512) void conv_apply_kernel(const float2* __restrict__ Uf,
                                                         const float2* __restrict__ Gf,
                                                         float* __restrict__ out) {
    int p = blockIdx.x;
    int b = blockIdx.y;
    __shared__ float re[FFT_N];
    __shared__ float im[FFT_N];
    const float2* Ub = Uf + (size_t)b * FFT_N;
    const float2* G0 = Gf + (size_t)(2 * p) * FFT_N;
    const float2* G1 = Gf + (size_t)(2 * p + 1) * FFT_N;
    for (int f = threadIdx.x; f < FFT_N; f += 512) {
        float2 uv = Ub[f], g0 = G0[f], g1 = G1[f];
        float gr = g0.x - g1.y, gi = g0.y + g1.x;
        re[f] = uv.x * gr - uv.y * gi;
        im[f] = uv.x * gi + uv.y * gr;
    }
    fft_dit_inv(re, im);
    const float inv = 1.0f / (float)FFT_N;
    for (int t = threadIdx.x; t < T; t += 512) {
        size_t idx = ((size_t)(b * T + t)) * HID + 2 * p;
        float2 xw = *(const float2*)(out + idx);
        float v0 = fmaxf(fmaf(re[t], inv, xw.x), 0.f);
        float v1 = fmaxf(fmaf(im[t], inv, xw.y), 0.f);
        *(float2*)(out + idx) = make_float2(v0, v1);
        if (t == T - 1) {
            size_t hn = (size_t)BATCH * T * HID + (size_t)b * HID + 2 * p;
            *(float2*)(out + hn) = make_float2(v0, v1);
        }
    }
}

// ============================== launch ==============================
extern "C" void kernel_launch(void* const* d_in, const int* in_sizes, int n_in,
                              void* d_out, int out_size, void* d_ws, size_t ws_size,
                              hipStream_t stream) {
    const float* x  = (const float*)d_in[0];   // 32*4096*256
    const float* Wu = (const float*)d_in[1];   // 256
    const float* Wh = (const float*)d_in[2];   // 512*512
    const float* H  = (const float*)d_in[3];   // 256*4096
    float* out = (float*)d_out;

    char* ws = (char*)d_ws;

    // new-path workspace layout (bytes)
    const size_t off_u   = 0;                                   // u: 0.5 MB
    const size_t off_t4i = 524288;                              // 32 KB (1360*3 float2)
    const size_t off_t2i = off_t4i + 32768;                     // 32 KB (4096 float2)
    const size_t off_t4f = off_t2i + 32768;                     // 32 KB
    const size_t off_t2f = off_t4f + 32768;                     // 32 KB
    const size_t off_xh  = off_t2f + 32768;                     // xh: 64 MB
    const size_t off_whf = off_xh + 67108864;                   // whfT: 0.5 MB
    const size_t off_U   = off_whf + 524288;                    // Uf: 2 MB
    const size_t off_Hf  = off_U  + 2097152;                    // Hf: 16 MB
    const size_t off_m2  = off_Hf + 16777216;                   // m2: 64 MB
    const size_t need    = off_m2 + (size_t)MEM * BT * 2;       // ~147.1 MB

    if (ws_size >= need) {
        float*     ws_u    = (float*)(ws + off_u);
        float2*    ws_t4i  = (float2*)(ws + off_t4i);
        float2*    ws_t2i  = (float2*)(ws + off_t2i);
        float2*    ws_t4f  = (float2*)(ws + off_t4f);
        float2*    ws_t2f  = (float2*)(ws + off_t2f);
        _Float16*  ws_xh   = (_Float16*)(ws + off_xh);
        _Float16*  ws_whfT = (_Float16*)(ws + off_whf);
        float2*    ws_U    = (float2*)(ws + off_U);
        float2*    ws_Hf   = (float2*)(ws + off_Hf);
        _Float16*  ws_m2   = (_Float16*)(ws + off_m2);

        twiddle_kernel<<<11, 512, 0, stream>>>(ws_t4f, ws_t2f, ws_t4i, ws_t2i);
        wh_pack_kernel<<<HID * HID / 4 / 256, 256, 0, stream>>>(Wh, ws_whfT);
        relu_u_kernel<<<BT / 4, 256, 0, stream>>>(x, Wu, ws_u, ws_xh);
        fwd_all_kernel<<<BATCH + MEM, 512, 0, stream>>>(ws_u, H, ws_t4f, ws_t2f, ws_U, ws_Hf);
        conv_m_kernel<<<dim3(MEM / 8, BATCH), 512, 0, stream>>>(ws_U, ws_Hf, ws_t4i, ws_t2i, ws_m2);
        h_gemm_kernel<<<dim3(HID / 128, BT / 128), 256, 0, stream>>>(ws_xh, ws_whfT, ws_m2, out);
    } else {
        // ---- old verified path (G-fold) ----
        float*  ws_u = (float*)ws;
        float2* ws_U = (float2*)(ws + 524288);
        float2* ws_G = (float2*)(ws + 524288 + 2097152);
        relu_u_only_kernel<<<BT / 4, 256, 0, stream>>>(x, Wu, ws_u);
        fft_u_kernel<<<BATCH, 512, 0, stream>>>(ws_u, ws_U);
        g_fft_kernel<<<HID, 512, 0, stream>>>(Wh, H, ws_G);
        xw_gemm_kernel<<<dim3(HID / 128, BATCH * T / 128), 256, 0, stream>>>(x, Wh, out);
        conv_apply_kernel<<<dim3(HID / 2, BATCH), 512, 0, stream>>>(ws_U, ws_G, out);
    }
}

// Round 5
// 706.981 us; speedup vs baseline: 1.0714x; 1.0714x over previous
//
#include <hip/hip_runtime.h>
#include <hip/hip_bf16.h>
#include <math.h>

// LMU-FFT: x(32,4096,256), W_u(1,256), W_h(512,512), H(256,4096) -> h(32,4096,512), h_n(32,512)
//
// Round-5 structure (iFFT-then-GEMM; round-4 math with spill-free codegen):
//   twiddles                   twiddle_kernel: (w,w2,w3) tables, L2-resident, sincos-exact
//   u = relu(x@W_u)            relu_u_kernel (also emits xh = fp16(x))
//   whfT = pack(W_h)           wh_pack_kernel (k-blocked fp16)
//   Uf, Hf = FFT(u), FFT(H)    fwd_all_kernel: R2 fused with zero-pad load (regs) ->
//                              LDS stages q=1024..16 (RUNTIME loop, table twiddles) ->
//                              q=4,1 in regs -> store
//   m = iFFT(Uf .* Hf-pairs)   conv_m_kernel: pointwise+q=1+q=4 in regs (literal
//                              twiddles) -> LDS stages q=16..1024 (RUNTIME loop,
//                              #pragma unroll 1: round-4's full unroll blew VGPR to
//                              128 + scratch spills, +240MB HBM traffic) -> R2 fused
//                              with scale+fp16 pack -> uint4 m2 store
//   h = relu([m|x] @ W_h^T)    h_gemm_kernel: 128x128 tile, BK=64, global_load_lds(16B)
//                              staging, 2-barrier K-loop, fp16 MFMA (unchanged, verified)

#define BATCH 32
#define T     4096
#define IND   256
#define HID   512
#define MEM   256
#define FFT_N 8192
#define FFT_LOG 13
#define BT    131072   // BATCH*T

typedef __attribute__((ext_vector_type(8))) short short8;
typedef __attribute__((ext_vector_type(8))) _Float16 half8;
typedef __attribute__((ext_vector_type(4))) float f32x4;

__device__ inline short f2bf(float f) {
    unsigned u = __float_as_uint(f);
    unsigned r = (u + 0x7FFFu + ((u >> 16) & 1u)) >> 16;
    return (short)r;
}
__device__ inline unsigned pk2h(float a, float b) {
    union { _Float16 h[2]; unsigned u; } v;
    v.h[0] = (_Float16)a; v.h[1] = (_Float16)b;
    return v.u;
}
__device__ __forceinline__ void gl_lds16(const void* g, void* l) {
    __builtin_amdgcn_global_load_lds((const __attribute__((address_space(1))) unsigned*)g,
                                     (__attribute__((address_space(3))) unsigned*)l, 16, 0, 0);
}

// ============================ kernel 0: twiddle tables ============================
// t4*: 1360 entries x (w,w2,w3) for R4 stages: q=16 @0, q=64 @16, q=256 @80, q=1024 @336
// t2*: 4096 entries (w) for the R2 half=4096 stage. inv: +sn; fwd: -sn.
__global__ __launch_bounds__(512) void twiddle_kernel(float2* __restrict__ t4f,
                                                      float2* __restrict__ t2f,
                                                      float2* __restrict__ t4i,
                                                      float2* __restrict__ t2i) {
    int i = blockIdx.x * 512 + threadIdx.x;
    if (i < 4096) {
        float a = ((float)M_PI / 4096.f) * (float)i;
        float sn, cs; __sincosf(a, &sn, &cs);
        t2i[i] = make_float2(cs, sn);
        t2f[i] = make_float2(cs, -sn);
    } else if (i < 4096 + 1360) {
        int e = i - 4096;
        int q, j;
        if (e < 16)       { q = 16;   j = e; }
        else if (e < 80)  { q = 64;   j = e - 16; }
        else if (e < 336) { q = 256;  j = e - 80; }
        else              { q = 1024; j = e - 336; }
        float a = ((float)M_PI / (float)(2 * q)) * (float)j;
        float sn, cs; __sincosf(a, &sn, &cs);
        float w2r = cs * cs - sn * sn, w2i = 2.f * cs * sn;
        float w3r = w2r * cs - w2i * sn, w3i = w2r * sn + w2i * cs;
        t4i[e * 3 + 0] = make_float2(cs, sn);
        t4i[e * 3 + 1] = make_float2(w2r, w2i);
        t4i[e * 3 + 2] = make_float2(w3r, w3i);
        t4f[e * 3 + 0] = make_float2(cs, -sn);
        t4f[e * 3 + 1] = make_float2(w2r, -w2i);
        t4f[e * 3 + 2] = make_float2(w3r, -w3i);
    }
}

// ============================ kernel 1 ============================
__global__ __launch_bounds__(256) void relu_u_kernel(const float* __restrict__ x,
                                                     const float* __restrict__ Wu,
                                                     float* __restrict__ u,
                                                     _Float16* __restrict__ xh) {
    int wave = threadIdx.x >> 6, lane = threadIdx.x & 63;
    int r = blockIdx.x * 4 + wave;
    const float4 xv = *(const float4*)(x + (size_t)r * IND + lane * 4);
    const float4 wv = *(const float4*)(Wu + lane * 4);
    union { _Float16 h[4]; uint2 u2; } hv;
    hv.h[0] = (_Float16)xv.x; hv.h[1] = (_Float16)xv.y;
    hv.h[2] = (_Float16)xv.z; hv.h[3] = (_Float16)xv.w;
    *(uint2*)(xh + (size_t)r * IND + lane * 4) = hv.u2;
    float acc = xv.x * wv.x + xv.y * wv.y + xv.z * wv.z + xv.w * wv.w;
    for (int off = 32; off; off >>= 1) acc += __shfl_down(acc, off);
    if (lane == 0) u[r] = fmaxf(acc, 0.f);
}
__global__ __launch_bounds__(256) void relu_u_only_kernel(const float* __restrict__ x,
                                                          const float* __restrict__ Wu,
                                                          float* __restrict__ u) {
    int wave = threadIdx.x >> 6, lane = threadIdx.x & 63;
    int r = blockIdx.x * 4 + wave;
    const float4 xv = *(const float4*)(x + (size_t)r * IND + lane * 4);
    const float4 wv = *(const float4*)(Wu + lane * 4);
    float acc = xv.x * wv.x + xv.y * wv.y + xv.z * wv.z + xv.w * wv.w;
    for (int off = 32; off; off >>= 1) acc += __shfl_down(acc, off);
    if (lane == 0) u[r] = fmaxf(acc, 0.f);
}

// ============================ kernel 1b ============================
__global__ __launch_bounds__(256) void wh_pack_kernel(const float* __restrict__ Wh,
                                                      _Float16* __restrict__ whfT) {
    int i = blockIdx.x * 256 + threadIdx.x;
    int col = i >> 7;
    int kq  = (i & 127) << 2;
    float4 v = *(const float4*)(Wh + (size_t)col * HID + kq);
    _Float16* d = whfT + (size_t)(kq >> 3) * (HID * 8) + (size_t)col * 8 + (kq & 7);
    d[0] = (_Float16)v.x; d[1] = (_Float16)v.y;
    d[2] = (_Float16)v.z; d[3] = (_Float16)v.w;
}

// ============================ kernel 2: forward FFTs ============================
// blocks 0..31: u rows -> Uf; blocks 32..287: H rows -> Hf. Digit-reversed output.
__global__ __launch_bounds__(512) void fwd_all_kernel(const float* __restrict__ u,
                                                      const float* __restrict__ H,
                                                      const float2* __restrict__ t4f,
                                                      const float2* __restrict__ t2f,
                                                      float2* __restrict__ Uf,
                                                      float2* __restrict__ Hf) {
    __shared__ float re[FFT_N];
    __shared__ float im[FFT_N];
    int r = blockIdx.x;
    int n = threadIdx.x;
    const float* src = (r < BATCH) ? (u + (size_t)r * T) : (H + (size_t)(r - BATCH) * T);
    float2* dst = (r < BATCH) ? (Uf + (size_t)r * FFT_N) : (Hf + (size_t)(r - BATCH) * FFT_N);

    // ---- R2 stage (half=4096) fused with load + zero-pad: k = 8n..8n+7, upper input = 0
    {
        float4 s0 = *(const float4*)(src + 8 * n);
        float4 s1 = *(const float4*)(src + 8 * n + 4);
        float2 w8[8];
        *(float4*)&w8[0] = *(const float4*)(t2f + 8 * n);
        *(float4*)&w8[2] = *(const float4*)(t2f + 8 * n + 2);
        *(float4*)&w8[4] = *(const float4*)(t2f + 8 * n + 4);
        *(float4*)&w8[6] = *(const float4*)(t2f + 8 * n + 6);
        *(float4*)&re[8 * n]     = s0;
        *(float4*)&re[8 * n + 4] = s1;
        float4 z = make_float4(0.f, 0.f, 0.f, 0.f);
        *(float4*)&im[8 * n]     = z;
        *(float4*)&im[8 * n + 4] = z;
        float4 ru0 = make_float4(w8[0].x * s0.x, w8[1].x * s0.y, w8[2].x * s0.z, w8[3].x * s0.w);
        float4 ru1 = make_float4(w8[4].x * s1.x, w8[5].x * s1.y, w8[6].x * s1.z, w8[7].x * s1.w);
        float4 iu0 = make_float4(w8[0].y * s0.x, w8[1].y * s0.y, w8[2].y * s0.z, w8[3].y * s0.w);
        float4 iu1 = make_float4(w8[4].y * s1.x, w8[5].y * s1.y, w8[6].y * s1.z, w8[7].y * s1.w);
        *(float4*)&re[8 * n + 4096]     = ru0;
        *(float4*)&re[8 * n + 4096 + 4] = ru1;
        *(float4*)&im[8 * n + 4096]     = iu0;
        *(float4*)&im[8 * n + 4096 + 4] = iu1;
    }
    __syncthreads();
    // ---- R4 LDS stages q = 1024, 256, 64, 16 (DIF order, table twiddles)
    // runtime loop (unroll 1): full unroll inflates liveness -> spills (round-4 lesson)
#pragma unroll 1
    for (int st = 10; st >= 4; st -= 2) {
        int q = 1 << st;
        int toff = (st == 4) ? 0 : (st == 6) ? 16 : (st == 8) ? 80 : 336;
#pragma unroll
        for (int s = 0; s < 4; ++s) {
            int k = n + s * 512;
            int j = k & (q - 1);
            int i0 = ((k >> st) << (st + 2)) + j;
            const float2* tw = t4f + (size_t)(toff + j) * 3;
            float2 W1 = tw[0], W2 = tw[1], W3 = tw[2];
            float ar = re[i0],         ai = im[i0];
            float br = re[i0 + q],     bi = im[i0 + q];
            float cr = re[i0 + 2 * q], ci = im[i0 + 2 * q];
            float dr = re[i0 + 3 * q], di = im[i0 + 3 * q];
            float t0r = ar + cr, t0i = ai + ci;
            float t1r = ar - cr, t1i = ai - ci;
            float t2r = br + dr, t2i = bi + di;
            float t3r = bi - di, t3i = dr - br;
            re[i0] = t0r + t2r;               im[i0] = t0i + t2i;
            float er = t0r - t2r, ei = t0i - t2i;
            re[i0 + q] = er * W2.x - ei * W2.y;     im[i0 + q] = er * W2.y + ei * W2.x;
            float fr = t1r + t3r, fi = t1i + t3i;
            re[i0 + 2 * q] = fr * W1.x - fi * W1.y; im[i0 + 2 * q] = fr * W1.y + fi * W1.x;
            float gr = t1r - t3r, gi = t1i - t3i;
            re[i0 + 3 * q] = gr * W3.x - gi * W3.y; im[i0 + 3 * q] = gr * W3.y + gi * W3.x;
        }
        __syncthreads();
    }
    // ---- final q=4 and q=1 stages in registers (thread owns [16n,16n+16)), store
    {
        float pr[16], pi[16];
#pragma unroll
        for (int s4 = 0; s4 < 4; ++s4) {
            *(float4*)&pr[4 * s4] = *(float4*)&re[16 * n + 4 * s4];
            *(float4*)&pi[4 * s4] = *(float4*)&im[16 * n + 4 * s4];
        }
        // q=4 (fwd): j = 0..3, w = exp(-i pi j / 8)  (literal twiddles, const-folded)
        const float TC[4] = {1.f, 0.92387953251f, 0.70710678119f, 0.38268343236f};
        const float TS[4] = {0.f, -0.38268343236f, -0.70710678119f, -0.92387953251f};
#pragma unroll
        for (int j = 0; j < 4; ++j) {
            float cs = TC[j], sn = TS[j];
            float w2r = cs * cs - sn * sn, w2i = 2.f * cs * sn;
            float w3r = w2r * cs - w2i * sn, w3i = w2r * sn + w2i * cs;
            float ar = pr[j], ai = pi[j], br = pr[j + 4], bi = pi[j + 4];
            float cr = pr[j + 8], ci = pi[j + 8], dr = pr[j + 12], di = pi[j + 12];
            float t0r = ar + cr, t0i = ai + ci;
            float t1r = ar - cr, t1i = ai - ci;
            float t2r = br + dr, t2i = bi + di;
            float t3r = bi - di, t3i = dr - br;
            pr[j] = t0r + t2r; pi[j] = t0i + t2i;
            float er = t0r - t2r, ei = t0i - t2i;
            pr[j + 4] = er * w2r - ei * w2i;  pi[j + 4] = er * w2i + ei * w2r;
            float fr = t1r + t3r, fi = t1i + t3i;
            pr[j + 8] = fr * cs - fi * sn;    pi[j + 8] = fr * sn + fi * cs;
            float gr = t1r - t3r, gi = t1i - t3i;
            pr[j + 12] = gr * w3r - gi * w3i; pi[j + 12] = gr * w3i + gi * w3r;
        }
        // q=1 (twiddle-free)
#pragma unroll
        for (int g = 0; g < 4; ++g) {
            float ar = pr[4 * g], ai = pi[4 * g], br = pr[4 * g + 1], bi = pi[4 * g + 1];
            float cr = pr[4 * g + 2], ci = pi[4 * g + 2], dr = pr[4 * g + 3], di = pi[4 * g + 3];
            float t0r = ar + cr, t0i = ai + ci;
            float t1r = ar - cr, t1i = ai - ci;
            float t2r = br + dr, t2i = bi + di;
            float t3r = bi - di, t3i = dr - br;
            pr[4 * g]     = t0r + t2r; pi[4 * g]     = t0i + t2i;
            pr[4 * g + 1] = t0r - t2r; pi[4 * g + 1] = t0i - t2i;
            pr[4 * g + 2] = t1r + t3r; pi[4 * g + 2] = t1i + t3i;
            pr[4 * g + 3] = t1r - t3r; pi[4 * g + 3] = t1i - t3i;
        }
#pragma unroll
        for (int e = 0; e < 8; ++e) {
            float4 o = make_float4(pr[2 * e], pi[2 * e], pr[2 * e + 1], pi[2 * e + 1]);
            *(float4*)&dst[16 * n + 2 * e] = o;
        }
    }
}

// ============================ kernel 3: iFFT + pack ============================
// per (qblock, b): 4 iFFTs (8 q-channels). pointwise + q=1 + q=4 in registers
// (literal twiddles), LDS stages q=16..1024 via RUNTIME loop (unroll 1 - round-4's
// full unroll caused 128-VGPR spills), R2-last fused with scale + fp16 pack.
__global__ __launch_bounds__(512) void conv_m_kernel(const float2* __restrict__ Uf,
                                                     const float2* __restrict__ Hf,
                                                     const float2* __restrict__ t4i,
                                                     const float2* __restrict__ t2i,
                                                     _Float16* __restrict__ m2) {
    int qb = blockIdx.x;   // 0..31
    int b  = blockIdx.y;   // 0..31
    int n  = threadIdx.x;
    __shared__ float re[FFT_N];
    __shared__ float im[FFT_N];
    const float2* Ub = Uf + (size_t)b * FFT_N;
    const float inv = 1.0f / (float)FFT_N;
    unsigned pk0[8], pk1[8], pk2[8], pk3[8];

#define CONV_FF(FF, PK)                                                          \
    {                                                                            \
        const float2* Ha = Hf + (size_t)(qb * 8 + 2 * (FF)) * FFT_N;             \
        const float2* Hb = Ha + FFT_N;                                           \
        float pr[16], pi[16];                                                    \
        _Pragma("unroll")                                                        \
        for (int e = 0; e < 16; ++e) {                                           \
            int f = 16 * n + e;                                                  \
            float2 uv = Ub[f], h0 = Ha[f], h1 = Hb[f];                           \
            float gr = h0.x - h1.y, gi = h0.y + h1.x;                            \
            pr[e] = uv.x * gr - uv.y * gi;                                       \
            pi[e] = uv.x * gi + uv.y * gr;                                       \
        }                                                                        \
        _Pragma("unroll")  /* inv q=1, twiddle-free */                           \
        for (int g = 0; g < 4; ++g) {                                            \
            float Ar = pr[4*g], Ai = pi[4*g], Br = pr[4*g+1], Bi = pi[4*g+1];    \
            float Cr = pr[4*g+2], Ci = pi[4*g+2], Dr = pr[4*g+3], Di = pi[4*g+3];\
            float t0r = Ar+Br, t0i = Ai+Bi, t2r = Ar-Br, t2i = Ai-Bi;            \
            float t1r = Cr+Dr, t1i = Ci+Di, t3r = Cr-Dr, t3i = Ci-Di;            \
            pr[4*g]   = t0r+t1r; pi[4*g]   = t0i+t1i;                            \
            pr[4*g+2] = t0r-t1r; pi[4*g+2] = t0i-t1i;                            \
            pr[4*g+1] = t2r-t3i; pi[4*g+1] = t2i+t3r;                            \
            pr[4*g+3] = t2r+t3i; pi[4*g+3] = t2i-t3r;                            \
        }                                                                        \
        _Pragma("unroll")  /* inv q=4, literal twiddles (const-folded) */        \
        for (int j = 0; j < 4; ++j) {                                            \
            const float QC[4] = {1.f, 0.92387953251f, 0.70710678119f, 0.38268343236f}; \
            const float QS[4] = {0.f, 0.38268343236f, 0.70710678119f, 0.92387953251f}; \
            float cs = QC[j], sn = QS[j];                                        \
            float w2r = cs*cs - sn*sn, w2i = 2.f*cs*sn;                          \
            float w3r = w2r*cs - w2i*sn, w3i = w2r*sn + w2i*cs;                  \
            float Ar = pr[j], Ai = pi[j], Br = pr[j+4], Bi = pi[j+4];            \
            float Cr = pr[j+8], Ci = pi[j+8], Dr = pr[j+12], Di = pi[j+12];      \
            float bpr = Br*w2r - Bi*w2i, bpi = Br*w2i + Bi*w2r;                  \
            float cpr = Cr*cs - Ci*sn,   cpi = Cr*sn + Ci*cs;                    \
            float dpr = Dr*w3r - Di*w3i, dpi = Dr*w3i + Di*w3r;                  \
            float t0r = Ar+bpr, t0i = Ai+bpi, t2r = Ar-bpr, t2i = Ai-bpi;        \
            float t1r = cpr+dpr, t1i = cpi+dpi, t3r = cpr-dpr, t3i = cpi-dpi;    \
            pr[j]    = t0r+t1r; pi[j]    = t0i+t1i;                              \
            pr[j+8]  = t0r-t1r; pi[j+8]  = t0i-t1i;                              \
            pr[j+4]  = t2r-t3i; pi[j+4]  = t2i+t3r;                              \
            pr[j+12] = t2r+t3i; pi[j+12] = t2i-t3r;                              \
        }                                                                        \
        if ((FF) > 0) __syncthreads();  /* prev FF's R2 reads done */            \
        _Pragma("unroll")                                                        \
        for (int s4 = 0; s4 < 4; ++s4) {                                         \
            *(float4*)&re[16*n + 4*s4] = *(float4*)&pr[4*s4];                    \
            *(float4*)&im[16*n + 4*s4] = *(float4*)&pi[4*s4];                    \
        }                                                                        \
        __syncthreads();                                                         \
        _Pragma("unroll 1")  /* LDS stages q=16,64,256,1024 - runtime loop */    \
        for (int st = 4; st <= 10; st += 2) {                                    \
            int q = 1 << st;                                                     \
            int toff = (st == 4) ? 0 : (st == 6) ? 16 : (st == 8) ? 80 : 336;    \
            _Pragma("unroll")                                                    \
            for (int s = 0; s < 4; ++s) {                                        \
                int k = n + s * 512;                                             \
                int j = k & (q - 1);                                             \
                int i0 = ((k >> st) << (st + 2)) + j;                            \
                const float2* tw = t4i + (size_t)(toff + j) * 3;                 \
                float2 W1 = tw[0], W2 = tw[1], W3 = tw[2];                       \
                float Ar = re[i0],       Ai = im[i0];                            \
                float Br = re[i0+q],     Bi = im[i0+q];                          \
                float Cr = re[i0+2*q],   Ci = im[i0+2*q];                        \
                float Dr = re[i0+3*q],   Di = im[i0+3*q];                        \
                float bpr = Br*W2.x - Bi*W2.y, bpi = Br*W2.y + Bi*W2.x;          \
                float cpr = Cr*W1.x - Ci*W1.y, cpi = Cr*W1.y + Ci*W1.x;          \
                float dpr = Dr*W3.x - Di*W3.y, dpi = Dr*W3.y + Di*W3.x;          \
                float t0r = Ar+bpr, t0i = Ai+bpi, t2r = Ar-bpr, t2i = Ai-bpi;    \
                float t1r = cpr+dpr, t1i = cpi+dpi, t3r = cpr-dpr, t3i = cpi-dpi;\
                re[i0]       = t0r+t1r; im[i0]       = t0i+t1i;                  \
                re[i0+2*q]   = t0r-t1r; im[i0+2*q]   = t0i-t1i;                  \
                re[i0+q]     = t2r-t3i; im[i0+q]     = t2i+t3r;                  \
                re[i0+3*q]   = t2r+t3i; im[i0+3*q]   = t2i-t3r;                  \
            }                                                                    \
            __syncthreads();                                                     \
        }                                                                        \
        _Pragma("unroll")  /* R2-last fused + scale + pack (upper half unused) */\
        for (int s = 0; s < 8; ++s) {                                            \
            int k = n + 512 * s;                                                 \
            float2 W = t2i[k];                                                   \
            float br = re[k + 4096], bi = im[k + 4096];                          \
            float tr = W.x * br - W.y * bi, ti = W.x * bi + W.y * br;            \
            PK[s] = pk2h((re[k] + tr) * inv, (im[k] + ti) * inv);                \
        }                                                                        \
    }

    CONV_FF(0, pk0)
    CONV_FF(1, pk1)
    CONV_FF(2, pk2)
    CONV_FF(3, pk3)
#undef CONV_FF

    _Float16* dst = m2 + ((size_t)qb * BT + (size_t)b * T) * 8;
#pragma unroll
    for (int s = 0; s < 8; ++s) {
        int tt = n + 512 * s;
        uint4 w4;
        w4.x = pk0[s]; w4.y = pk1[s]; w4.z = pk2[s]; w4.w = pk3[s];
        *(uint4*)(dst + (size_t)tt * 8) = w4;
    }
}

// ============================ kernel 4: GEMM (unchanged, verified) ============================
__global__ __launch_bounds__(256) void h_gemm_kernel(const _Float16* __restrict__ xh,
                                                     const _Float16* __restrict__ whfT,
                                                     const _Float16* __restrict__ m2,
                                                     float* __restrict__ out) {
    __shared__ __align__(16) _Float16 As[8][128][8];
    __shared__ __align__(16) _Float16 Bs[8][128][8];
    int bn = blockIdx.x;
    int bm = blockIdx.y;
    int t = threadIdx.x;
    int wv = t >> 6, lane = t & 63;
    int wm = (wv & 1) * 64, wn = (wv >> 1) * 64;
    int ln = lane & 15, kg = lane >> 4;

    f32x4 acc[4][4] = {};
#pragma unroll
    for (int ks = 0; ks < 8; ++ks) {
        int kc = ks * 64;
        __syncthreads();
#pragma unroll
        for (int q = 0; q < 8; ++q) {
            int c = wv * 8 + q;
            int g = (c & 15) >> 1;
            int rg = c & 1;
            int row = rg * 64 + lane;
            if (c < 16) {
                const void* src;
                if (kc < MEM)
                    src = m2 + ((size_t)(kc / 8 + g) * BT + (size_t)bm * 128 + row) * 8;
                else
                    src = xh + (size_t)(bm * 128 + row) * IND + (kc - MEM) + g * 8;
                gl_lds16(src, &As[g][rg * 64][0]);
            } else {
                const void* src = whfT + (size_t)(kc / 8 + g) * (HID * 8)
                                       + (size_t)(bn * 128 + row) * 8;
                gl_lds16(src, &Bs[g][rg * 64][0]);
            }
        }
        __syncthreads();
        half8 af[2][4], bf[2][4];
#pragma unroll
        for (int kk = 0; kk < 2; ++kk) {
#pragma unroll
            for (int i = 0; i < 4; ++i)
                af[kk][i] = *(const half8*)&As[kk * 4 + kg][wm + i * 16 + ln][0];
#pragma unroll
            for (int j = 0; j < 4; ++j)
                bf[kk][j] = *(const half8*)&Bs[kk * 4 + kg][wn + j * 16 + ln][0];
        }
#pragma unroll
        for (int kk = 0; kk < 2; ++kk)
#pragma unroll
            for (int i = 0; i < 4; ++i)
#pragma unroll
                for (int j = 0; j < 4; ++j)
                    acc[i][j] = __builtin_amdgcn_mfma_f32_16x16x32_f16(af[kk][i], bf[kk][j],
                                                                       acc[i][j], 0, 0, 0);
    }
#pragma unroll
    for (int i = 0; i < 4; ++i) {
#pragma unroll
        for (int j = 0; j < 4; ++j) {
#pragma unroll
            for (int r = 0; r < 4; ++r) {
                int row = bm * 128 + wm + i * 16 + kg * 4 + r;
                int col = bn * 128 + wn + j * 16 + ln;
                float v = fmaxf(acc[i][j][r], 0.f);
                out[(size_t)row * HID + col] = v;
                if ((row & (T - 1)) == (T - 1))
                    out[(size_t)BATCH * T * HID + (size_t)(row >> 12) * HID + col] = v;
            }
        }
    }
}

// ================== OLD PATH (verbatim fallback, small ws) ==================
__device__ void fft_dif_fwd(float* re, float* im) {
    __syncthreads();
    for (int st = FFT_LOG; st >= 1; --st) {
        int half = 1 << (st - 1);
        float fm = -(float)M_PI / (float)half;
        for (int k = threadIdx.x; k < FFT_N / 2; k += 512) {
            int j  = k & (half - 1);
            int i1 = ((k >> (st - 1)) << st) + j;
            int i2 = i1 + half;
            float sn, cs;
            __sincosf(fm * (float)j, &sn, &cs);
            float ar = re[i1], ai = im[i1];
            float br = re[i2], bi = im[i2];
            re[i1] = ar + br; im[i1] = ai + bi;
            float dr = ar - br, di = ai - bi;
            re[i2] = cs * dr - sn * di;
            im[i2] = cs * di + sn * dr;
        }
        __syncthreads();
    }
}
__device__ void fft_dit_inv(float* re, float* im) {
    __syncthreads();
    for (int st = 1; st <= FFT_LOG; ++st) {
        int half = 1 << (st - 1);
        float fm = (float)M_PI / (float)half;
        for (int k = threadIdx.x; k < FFT_N / 2; k += 512) {
            int j  = k & (half - 1);
            int i1 = ((k >> (st - 1)) << st) + j;
            int i2 = i1 + half;
            float sn, cs;
            __sincosf(fm * (float)j, &sn, &cs);
            float br = re[i2], bi = im[i2];
            float tr = cs * br - sn * bi;
            float ti = cs * bi + sn * br;
            float ar = re[i1], ai = im[i1];
            re[i1] = ar + tr; im[i1] = ai + ti;
            re[i2] = ar - tr; im[i2] = ai - ti;
        }
        __syncthreads();
    }
}
__global__ __launch_bounds__(512) void fft_u_kernel(const float* __restrict__ u,
                                                    float2* __restrict__ Uf) {
    int b = blockIdx.x;
    __shared__ float re[FFT_N];
    __shared__ float im[FFT_N];
    for (int i = threadIdx.x; i < FFT_N; i += 512) {
        re[i] = i < T ? u[(size_t)b * T + i] : 0.f;
        im[i] = 0.f;
    }
    fft_dif_fwd(re, im);
    for (int i = threadIdx.x; i < FFT_N; i += 512)
        Uf[(size_t)b * FFT_N + i] = make_float2(re[i], im[i]);
}
__global__ __launch_bounds__(512) void g_fft_kernel(const float* __restrict__ Wh,
                                                    const float* __restrict__ H,
                                                    float2* __restrict__ Gf) {
    int o = blockIdx.x;
    __shared__ float re[FFT_N];
    __shared__ float im[FFT_N];
    const float* wrow = Wh + (size_t)o * HID;
    float acc[8];
#pragma unroll
    for (int d = 0; d < 8; ++d) acc[d] = 0.f;
    for (int q = 0; q < 256; ++q) {
        float w = wrow[q];
        const float* hrow = H + (size_t)q * T;
#pragma unroll
        for (int d = 0; d < 8; ++d)
            acc[d] = fmaf(w, hrow[threadIdx.x + d * 512], acc[d]);
    }
#pragma unroll
    for (int d = 0; d < 8; ++d) {
        re[threadIdx.x + d * 512] = acc[d];
        im[threadIdx.x + d * 512] = 0.f;
    }
    for (int i = T + threadIdx.x; i < FFT_N; i += 512) { re[i] = 0.f; im[i] = 0.f; }
    fft_dif_fwd(re, im);
    for (int i = threadIdx.x; i < FFT_N; i += 512)
        Gf[(size_t)o * FFT_N + i] = make_float2(re[i], im[i]);
}
__global__ __launch_bounds__(256) void xw_gemm_kernel(const float* __restrict__ x,
                                                      const float* __restrict__ Wh,
                                                      float* __restrict__ out) {
    __shared__ __align__(16) short Asl[4][128][8];
    __shared__ __align__(16) short Bsl[4][128][8];
    int bn = blockIdx.x;
    int bm = blockIdx.y;
    int t = threadIdx.x;
    int wv = t >> 6, lane = t & 63;
    int wm = (wv & 1) * 64, wn = (wv >> 1) * 64;
    int ln = lane & 15, kg = lane >> 4;
    f32x4 acc[4][4] = {};
    int mrow = t >> 1, khalf = t & 1;
    for (int kc = 0; kc < IND; kc += 32) {
        {
            const float* xr = x + ((size_t)(bm * 128 + mrow)) * IND + kc + khalf * 16;
            float4 v0 = *(const float4*)(xr + 0);
            float4 v1 = *(const float4*)(xr + 4);
            float4 v2 = *(const float4*)(xr + 8);
            float4 v3 = *(const float4*)(xr + 12);
            short8 s0 = { f2bf(v0.x), f2bf(v0.y), f2bf(v0.z), f2bf(v0.w),
                          f2bf(v1.x), f2bf(v1.y), f2bf(v1.z), f2bf(v1.w) };
            short8 s1 = { f2bf(v2.x), f2bf(v2.y), f2bf(v2.z), f2bf(v2.w),
                          f2bf(v3.x), f2bf(v3.y), f2bf(v3.z), f2bf(v3.w) };
            const float* wr = Wh + ((size_t)(bn * 128 + mrow)) * HID + 256 + kc + khalf * 16;
            float4 w0 = *(const float4*)(wr + 0);
            float4 w1 = *(const float4*)(wr + 4);
            float4 w2 = *(const float4*)(wr + 8);
            float4 w3 = *(const float4*)(wr + 12);
            short8 b0 = { f2bf(w0.x), f2bf(w0.y), f2bf(w0.z), f2bf(w0.w),
                          f2bf(w1.x), f2bf(w1.y), f2bf(w1.z), f2bf(w1.w) };
            short8 b1 = { f2bf(w2.x), f2bf(w2.y), f2bf(w2.z), f2bf(w2.w),
                          f2bf(w3.x), f2bf(w3.y), f2bf(w3.z), f2bf(w3.w) };
            __syncthreads();
            *(short8*)&Asl[khalf * 2 + 0][mrow][0] = s0;
            *(short8*)&Asl[khalf * 2 + 1][mrow][0] = s1;
            *(short8*)&Bsl[khalf * 2 + 0][mrow][0] = b0;
            *(short8*)&Bsl[khalf * 2 + 1][mrow][0] = b1;
            __syncthreads();
        }
        short8 af[4], bf[4];
#pragma unroll
        for (int i = 0; i < 4; ++i) af[i] = *(short8*)&Asl[kg][wm + i * 16 + ln][0];
#pragma unroll
        for (int j = 0; j < 4; ++j) bf[j] = *(short8*)&Bsl[kg][wn + j * 16 + ln][0];
#pragma unroll
        for (int i = 0; i < 4; ++i)
#pragma unroll
            for (int j = 0; j < 4; ++j)
                acc[i][j] = __builtin_amdgcn_mfma_f32_16x16x32_bf16(af[i], bf[j], acc[i][j], 0, 0, 0);
    }
#pragma unroll
    for (int i = 0; i < 4; ++i) {
#pragma unroll
        for (int j = 0; j < 4; ++j) {
#pragma unroll
            for (int r = 0; r < 4; ++r) {
                int row = bm * 128 + wm + i * 16 + (lane >> 4) * 4 + r;
                int col = bn * 128 + wn + j * 16 + (lane & 15);
                out[(size_t)row * HID + col] = acc[i][j][r];
            }
        }
    }
}
__global__ __launch_bounds__(512) void conv_apply_kernel(const float2* __restrict__ Uf,
                                                         const float2* __restrict__ Gf,
                                                         float* __restrict__ out) {
    int p = blockIdx.x;
    int b = blockIdx.y;
    __shared__ float re[FFT_N];
    __shared__ float im[FFT_N];
    const float2* Ub = Uf + (size_t)b * FFT_N;
    const float2* G0 = Gf + (size_t)(2 * p) * FFT_N;
    const float2* G1 = Gf + (size_t)(2 * p + 1) * FFT_N;
    for (int f = threadIdx.x; f < FFT_N; f += 512) {
        float2 uv = Ub[f], g0 = G0[f], g1 = G1[f];
        float gr = g0.x - g1.y, gi = g0.y + g1.x;
        re[f] = uv.x * gr - uv.y * gi;
        im[f] = uv.x * gi + uv.y * gr;
    }
    fft_dit_inv(re, im);
    const float inv = 1.0f / (float)FFT_N;
    for (int t = threadIdx.x; t < T; t += 512) {
        size_t idx = ((size_t)(b * T + t)) * HID + 2 * p;
        float2 xw = *(const float2*)(out + idx);
        float v0 = fmaxf(fmaf(re[t], inv, xw.x), 0.f);
        float v1 = fmaxf(fmaf(im[t], inv, xw.y), 0.f);
        *(float2*)(out + idx) = make_float2(v0, v1);
        if (t == T - 1) {
            size_t hn = (size_t)BATCH * T * HID + (size_t)b * HID + 2 * p;
            *(float2*)(out + hn) = make_float2(v0, v1);
        }
    }
}

// ============================== launch ==============================
extern "C" void kernel_launch(void* const* d_in, const int* in_sizes, int n_in,
                              void* d_out, int out_size, void* d_ws, size_t ws_size,
                              hipStream_t stream) {
    const float* x  = (const float*)d_in[0];   // 32*4096*256
    const float* Wu = (const float*)d_in[1];   // 256
    const float* Wh = (const float*)d_in[2];   // 512*512
    const float* H  = (const float*)d_in[3];   // 256*4096
    float* out = (float*)d_out;

    char* ws = (char*)d_ws;

    // new-path workspace layout (bytes)
    const size_t off_u   = 0;                                   // u: 0.5 MB
    const size_t off_t4i = 524288;                              // 32 KB (1360*3 float2)
    const size_t off_t2i = off_t4i + 32768;                     // 32 KB (4096 float2)
    const size_t off_t4f = off_t2i + 32768;                     // 32 KB
    const size_t off_t2f = off_t4f + 32768;                     // 32 KB
    const size_t off_xh  = off_t2f + 32768;                     // xh: 64 MB
    const size_t off_whf = off_xh + 67108864;                   // whfT: 0.5 MB
    const size_t off_U   = off_whf + 524288;                    // Uf: 2 MB
    const size_t off_Hf  = off_U  + 2097152;                    // Hf: 16 MB
    const size_t off_m2  = off_Hf + 16777216;                   // m2: 64 MB
    const size_t need    = off_m2 + (size_t)MEM * BT * 2;       // ~147.1 MB

    if (ws_size >= need) {
        float*     ws_u    = (float*)(ws + off_u);
        float2*    ws_t4i  = (float2*)(ws + off_t4i);
        float2*    ws_t2i  = (float2*)(ws + off_t2i);
        float2*    ws_t4f  = (float2*)(ws + off_t4f);
        float2*    ws_t2f  = (float2*)(ws + off_t2f);
        _Float16*  ws_xh   = (_Float16*)(ws + off_xh);
        _Float16*  ws_whfT = (_Float16*)(ws + off_whf);
        float2*    ws_U    = (float2*)(ws + off_U);
        float2*    ws_Hf   = (float2*)(ws + off_Hf);
        _Float16*  ws_m2   = (_Float16*)(ws + off_m2);

        twiddle_kernel<<<11, 512, 0, stream>>>(ws_t4f, ws_t2f, ws_t4i, ws_t2i);
        wh_pack_kernel<<<HID * HID / 4 / 256, 256, 0, stream>>>(Wh, ws_whfT);
        relu_u_kernel<<<BT / 4, 256, 0, stream>>>(x, Wu, ws_u, ws_xh);
        fwd_all_kernel<<<BATCH + MEM, 512, 0, stream>>>(ws_u, H, ws_t4f, ws_t2f, ws_U, ws_Hf);
        conv_m_kernel<<<dim3(MEM / 8, BATCH), 512, 0, stream>>>(ws_U, ws_Hf, ws_t4i, ws_t2i, ws_m2);
        h_gemm_kernel<<<dim3(HID / 128, BT / 128), 256, 0, stream>>>(ws_xh, ws_whfT, ws_m2, out);
    } else {
        // ---- old verified path (G-fold) ----
        float*  ws_u = (float*)ws;
        float2* ws_U = (float2*)(ws + 524288);
        float2* ws_G = (float2*)(ws + 524288 + 2097152);
        relu_u_only_kernel<<<BT / 4, 256, 0, stream>>>(x, Wu, ws_u);
        fft_u_kernel<<<BATCH, 512, 0, stream>>>(ws_u, ws_U);
        g_fft_kernel<<<HID, 512, 0, stream>>>(Wh, H, ws_G);
        xw_gemm_kernel<<<dim3(HID / 128, BATCH * T / 128), 256, 0, stream>>>(x, Wh, out);
        conv_apply_kernel<<<dim3(HID / 2, BATCH), 512, 0, stream>>>(ws_U, ws_G, out);
    }
}

// Round 6
// 656.736 us; speedup vs baseline: 1.1534x; 1.0765x over previous
//
#include <hip/hip_runtime.h>
#include <hip/hip_bf16.h>
#include <math.h>

// LMU-FFT: x(32,4096,256), W_u(1,256), W_h(512,512), H(256,4096) -> h(32,4096,512), h_n(32,512)
//
// Round-6 structure (iFFT-then-GEMM; lean conv_m: round-3 skeleton + cheap fusions):
//   twiddles                   twiddle_kernel: (w,w2,w3) tables incl. q=4; L2-resident
//   u = relu(x@W_u)            relu_u_kernel (also emits xh = fp16(x))
//   whfT = pack(W_h)           wh_pack_kernel (k-blocked fp16)
//   Uf, Hf = FFT(u), FFT(H)    fwd_all_kernel: R2 fused with zero-pad load (regs) ->
//                              LDS stages q=1024..16 (runtime loop, table twiddles) ->
//                              q=4,1 in regs -> store
//   m = iFFT(Uf .* Hf-pairs)   conv_m_kernel: pointwise + q=1 fused in 4-elem register
//                              chunks (8 live floats - NOT the 16-elem/32-reg fusion of
//                              rounds 4/5 which tanked occupancy) -> LDS stages q=4..1024
//                              (runtime loop, table twiddles) -> R2 fused with scale +
//                              fp16 pack (upper half never computed) -> uint4 m2 store
//   h = relu([m|x] @ W_h^T)    h_gemm_kernel: 128x128 tile, BK=64, global_load_lds(16B)
//                              staging, 2-barrier K-loop, fp16 MFMA (unchanged, verified)

#define BATCH 32
#define T     4096
#define IND   256
#define HID   512
#define MEM   256
#define FFT_N 8192
#define FFT_LOG 13
#define BT    131072   // BATCH*T

typedef __attribute__((ext_vector_type(8))) short short8;
typedef __attribute__((ext_vector_type(8))) _Float16 half8;
typedef __attribute__((ext_vector_type(4))) float f32x4;

__device__ inline short f2bf(float f) {
    unsigned u = __float_as_uint(f);
    unsigned r = (u + 0x7FFFu + ((u >> 16) & 1u)) >> 16;
    return (short)r;
}
__device__ inline unsigned pk2h(float a, float b) {
    union { _Float16 h[2]; unsigned u; } v;
    v.h[0] = (_Float16)a; v.h[1] = (_Float16)b;
    return v.u;
}
__device__ __forceinline__ void gl_lds16(const void* g, void* l) {
    __builtin_amdgcn_global_load_lds((const __attribute__((address_space(1))) unsigned*)g,
                                     (__attribute__((address_space(3))) unsigned*)l, 16, 0, 0);
}

// ============================ kernel 0: twiddle tables ============================
// t4*: 1364 entries x (w,w2,w3) for R4 stages: q=4 @0, q=16 @4, q=64 @20, q=256 @84,
//      q=1024 @340.  t2*: 4096 entries (w) for the R2 half=4096 stage.
// inv: +sn; fwd: -sn. Same __sincosf as the verified in-kernel computation.
__global__ __launch_bounds__(512) void twiddle_kernel(float2* __restrict__ t4f,
                                                      float2* __restrict__ t2f,
                                                      float2* __restrict__ t4i,
                                                      float2* __restrict__ t2i) {
    int i = blockIdx.x * 512 + threadIdx.x;
    if (i < 4096) {
        float a = ((float)M_PI / 4096.f) * (float)i;
        float sn, cs; __sincosf(a, &sn, &cs);
        t2i[i] = make_float2(cs, sn);
        t2f[i] = make_float2(cs, -sn);
    } else if (i < 4096 + 1364) {
        int e = i - 4096;
        int q, j;
        if (e < 4)        { q = 4;    j = e; }
        else if (e < 20)  { q = 16;   j = e - 4; }
        else if (e < 84)  { q = 64;   j = e - 20; }
        else if (e < 340) { q = 256;  j = e - 84; }
        else              { q = 1024; j = e - 340; }
        float a = ((float)M_PI / (float)(2 * q)) * (float)j;
        float sn, cs; __sincosf(a, &sn, &cs);
        float w2r = cs * cs - sn * sn, w2i = 2.f * cs * sn;
        float w3r = w2r * cs - w2i * sn, w3i = w2r * sn + w2i * cs;
        t4i[e * 3 + 0] = make_float2(cs, sn);
        t4i[e * 3 + 1] = make_float2(w2r, w2i);
        t4i[e * 3 + 2] = make_float2(w3r, w3i);
        t4f[e * 3 + 0] = make_float2(cs, -sn);
        t4f[e * 3 + 1] = make_float2(w2r, -w2i);
        t4f[e * 3 + 2] = make_float2(w3r, -w3i);
    }
}

// ============================ kernel 1 ============================
__global__ __launch_bounds__(256) void relu_u_kernel(const float* __restrict__ x,
                                                     const float* __restrict__ Wu,
                                                     float* __restrict__ u,
                                                     _Float16* __restrict__ xh) {
    int wave = threadIdx.x >> 6, lane = threadIdx.x & 63;
    int r = blockIdx.x * 4 + wave;
    const float4 xv = *(const float4*)(x + (size_t)r * IND + lane * 4);
    const float4 wv = *(const float4*)(Wu + lane * 4);
    union { _Float16 h[4]; uint2 u2; } hv;
    hv.h[0] = (_Float16)xv.x; hv.h[1] = (_Float16)xv.y;
    hv.h[2] = (_Float16)xv.z; hv.h[3] = (_Float16)xv.w;
    *(uint2*)(xh + (size_t)r * IND + lane * 4) = hv.u2;
    float acc = xv.x * wv.x + xv.y * wv.y + xv.z * wv.z + xv.w * wv.w;
    for (int off = 32; off; off >>= 1) acc += __shfl_down(acc, off);
    if (lane == 0) u[r] = fmaxf(acc, 0.f);
}
__global__ __launch_bounds__(256) void relu_u_only_kernel(const float* __restrict__ x,
                                                          const float* __restrict__ Wu,
                                                          float* __restrict__ u) {
    int wave = threadIdx.x >> 6, lane = threadIdx.x & 63;
    int r = blockIdx.x * 4 + wave;
    const float4 xv = *(const float4*)(x + (size_t)r * IND + lane * 4);
    const float4 wv = *(const float4*)(Wu + lane * 4);
    float acc = xv.x * wv.x + xv.y * wv.y + xv.z * wv.z + xv.w * wv.w;
    for (int off = 32; off; off >>= 1) acc += __shfl_down(acc, off);
    if (lane == 0) u[r] = fmaxf(acc, 0.f);
}

// ============================ kernel 1b ============================
__global__ __launch_bounds__(256) void wh_pack_kernel(const float* __restrict__ Wh,
                                                      _Float16* __restrict__ whfT) {
    int i = blockIdx.x * 256 + threadIdx.x;
    int col = i >> 7;
    int kq  = (i & 127) << 2;
    float4 v = *(const float4*)(Wh + (size_t)col * HID + kq);
    _Float16* d = whfT + (size_t)(kq >> 3) * (HID * 8) + (size_t)col * 8 + (kq & 7);
    d[0] = (_Float16)v.x; d[1] = (_Float16)v.y;
    d[2] = (_Float16)v.z; d[3] = (_Float16)v.w;
}

// ============================ kernel 2: forward FFTs ============================
// blocks 0..31: u rows -> Uf; blocks 32..287: H rows -> Hf. Digit-reversed output.
__global__ __launch_bounds__(512) void fwd_all_kernel(const float* __restrict__ u,
                                                      const float* __restrict__ H,
                                                      const float2* __restrict__ t4f,
                                                      const float2* __restrict__ t2f,
                                                      float2* __restrict__ Uf,
                                                      float2* __restrict__ Hf) {
    __shared__ float re[FFT_N];
    __shared__ float im[FFT_N];
    int r = blockIdx.x;
    int n = threadIdx.x;
    const float* src = (r < BATCH) ? (u + (size_t)r * T) : (H + (size_t)(r - BATCH) * T);
    float2* dst = (r < BATCH) ? (Uf + (size_t)r * FFT_N) : (Hf + (size_t)(r - BATCH) * FFT_N);

    // ---- R2 stage (half=4096) fused with load + zero-pad: k = 8n..8n+7, upper input = 0
    {
        float4 s0 = *(const float4*)(src + 8 * n);
        float4 s1 = *(const float4*)(src + 8 * n + 4);
        float2 w8[8];
        *(float4*)&w8[0] = *(const float4*)(t2f + 8 * n);
        *(float4*)&w8[2] = *(const float4*)(t2f + 8 * n + 2);
        *(float4*)&w8[4] = *(const float4*)(t2f + 8 * n + 4);
        *(float4*)&w8[6] = *(const float4*)(t2f + 8 * n + 6);
        *(float4*)&re[8 * n]     = s0;
        *(float4*)&re[8 * n + 4] = s1;
        float4 z = make_float4(0.f, 0.f, 0.f, 0.f);
        *(float4*)&im[8 * n]     = z;
        *(float4*)&im[8 * n + 4] = z;
        float4 ru0 = make_float4(w8[0].x * s0.x, w8[1].x * s0.y, w8[2].x * s0.z, w8[3].x * s0.w);
        float4 ru1 = make_float4(w8[4].x * s1.x, w8[5].x * s1.y, w8[6].x * s1.z, w8[7].x * s1.w);
        float4 iu0 = make_float4(w8[0].y * s0.x, w8[1].y * s0.y, w8[2].y * s0.z, w8[3].y * s0.w);
        float4 iu1 = make_float4(w8[4].y * s1.x, w8[5].y * s1.y, w8[6].y * s1.z, w8[7].y * s1.w);
        *(float4*)&re[8 * n + 4096]     = ru0;
        *(float4*)&re[8 * n + 4096 + 4] = ru1;
        *(float4*)&im[8 * n + 4096]     = iu0;
        *(float4*)&im[8 * n + 4096 + 4] = iu1;
    }
    __syncthreads();
    // ---- R4 LDS stages q = 1024, 256, 64, 16 (DIF order, table twiddles)
#pragma unroll 1
    for (int st = 10; st >= 4; st -= 2) {
        int q = 1 << st;
        int toff = (st == 4) ? 4 : (st == 6) ? 20 : (st == 8) ? 84 : 340;
#pragma unroll
        for (int s = 0; s < 4; ++s) {
            int k = n + s * 512;
            int j = k & (q - 1);
            int i0 = ((k >> st) << (st + 2)) + j;
            const float2* tw = t4f + (size_t)(toff + j) * 3;
            float2 W1 = tw[0], W2 = tw[1], W3 = tw[2];
            float ar = re[i0],         ai = im[i0];
            float br = re[i0 + q],     bi = im[i0 + q];
            float cr = re[i0 + 2 * q], ci = im[i0 + 2 * q];
            float dr = re[i0 + 3 * q], di = im[i0 + 3 * q];
            float t0r = ar + cr, t0i = ai + ci;
            float t1r = ar - cr, t1i = ai - ci;
            float t2r = br + dr, t2i = bi + di;
            float t3r = bi - di, t3i = dr - br;
            re[i0] = t0r + t2r;               im[i0] = t0i + t2i;
            float er = t0r - t2r, ei = t0i - t2i;
            re[i0 + q] = er * W2.x - ei * W2.y;     im[i0 + q] = er * W2.y + ei * W2.x;
            float fr = t1r + t3r, fi = t1i + t3i;
            re[i0 + 2 * q] = fr * W1.x - fi * W1.y; im[i0 + 2 * q] = fr * W1.y + fi * W1.x;
            float gr = t1r - t3r, gi = t1i - t3i;
            re[i0 + 3 * q] = gr * W3.x - gi * W3.y; im[i0 + 3 * q] = gr * W3.y + gi * W3.x;
        }
        __syncthreads();
    }
    // ---- final q=4 and q=1 stages in registers (thread owns [16n,16n+16)), store
    {
        float pr[16], pi[16];
#pragma unroll
        for (int s4 = 0; s4 < 4; ++s4) {
            *(float4*)&pr[4 * s4] = *(float4*)&re[16 * n + 4 * s4];
            *(float4*)&pi[4 * s4] = *(float4*)&im[16 * n + 4 * s4];
        }
        // q=4 (fwd): j = 0..3, w = exp(-i pi j / 8)  (literal twiddles, const-folded)
        const float TC[4] = {1.f, 0.92387953251f, 0.70710678119f, 0.38268343236f};
        const float TS[4] = {0.f, -0.38268343236f, -0.70710678119f, -0.92387953251f};
#pragma unroll
        for (int j = 0; j < 4; ++j) {
            float cs = TC[j], sn = TS[j];
            float w2r = cs * cs - sn * sn, w2i = 2.f * cs * sn;
            float w3r = w2r * cs - w2i * sn, w3i = w2r * sn + w2i * cs;
            float ar = pr[j], ai = pi[j], br = pr[j + 4], bi = pi[j + 4];
            float cr = pr[j + 8], ci = pi[j + 8], dr = pr[j + 12], di = pi[j + 12];
            float t0r = ar + cr, t0i = ai + ci;
            float t1r = ar - cr, t1i = ai - ci;
            float t2r = br + dr, t2i = bi + di;
            float t3r = bi - di, t3i = dr - br;
            pr[j] = t0r + t2r; pi[j] = t0i + t2i;
            float er = t0r - t2r, ei = t0i - t2i;
            pr[j + 4] = er * w2r - ei * w2i;  pi[j + 4] = er * w2i + ei * w2r;
            float fr = t1r + t3r, fi = t1i + t3i;
            pr[j + 8] = fr * cs - fi * sn;    pi[j + 8] = fr * sn + fi * cs;
            float gr = t1r - t3r, gi = t1i - t3i;
            pr[j + 12] = gr * w3r - gi * w3i; pi[j + 12] = gr * w3i + gi * w3r;
        }
        // q=1 (twiddle-free)
#pragma unroll
        for (int g = 0; g < 4; ++g) {
            float ar = pr[4 * g], ai = pi[4 * g], br = pr[4 * g + 1], bi = pi[4 * g + 1];
            float cr = pr[4 * g + 2], ci = pi[4 * g + 2], dr = pr[4 * g + 3], di = pi[4 * g + 3];
            float t0r = ar + cr, t0i = ai + ci;
            float t1r = ar - cr, t1i = ai - ci;
            float t2r = br + dr, t2i = bi + di;
            float t3r = bi - di, t3i = dr - br;
            pr[4 * g]     = t0r + t2r; pi[4 * g]     = t0i + t2i;
            pr[4 * g + 1] = t0r - t2r; pi[4 * g + 1] = t0i - t2i;
            pr[4 * g + 2] = t1r + t3r; pi[4 * g + 2] = t1i + t3i;
            pr[4 * g + 3] = t1r - t3r; pi[4 * g + 3] = t1i - t3i;
        }
#pragma unroll
        for (int e = 0; e < 8; ++e) {
            float4 o = make_float4(pr[2 * e], pi[2 * e], pr[2 * e + 1], pi[2 * e + 1]);
            *(float4*)&dst[16 * n + 2 * e] = o;
        }
    }
}

// ============================ kernel 3: iFFT + pack ============================
// per (qblock, b): 4 iFFTs (8 q-channels).
// pointwise + q=1 fused in 4-element register chunks (8 live floats);
// LDS stages q=4..1024 (runtime loop, table twiddles);
// R2-last fused with scale + fp16 pack (upper half never computed).
__global__ __launch_bounds__(512) void conv_m_kernel(const float2* __restrict__ Uf,
                                                     const float2* __restrict__ Hf,
                                                     const float2* __restrict__ t4i,
                                                     const float2* __restrict__ t2i,
                                                     _Float16* __restrict__ m2) {
    int qb = blockIdx.x;   // 0..31
    int b  = blockIdx.y;   // 0..31
    int n  = threadIdx.x;
    __shared__ float re[FFT_N];
    __shared__ float im[FFT_N];
    const float2* Ub = Uf + (size_t)b * FFT_N;
    const float inv = 1.0f / (float)FFT_N;
    unsigned pk0[8], pk1[8], pk2[8], pk3[8];

#define CONV_FF(FF, PK)                                                          \
    {                                                                            \
        const float2* Ha = Hf + (size_t)(qb * 8 + 2 * (FF)) * FFT_N;             \
        const float2* Hb = Ha + FFT_N;                                           \
        if ((FF) > 0) __syncthreads();  /* prev FF's R2 reads done */            \
        _Pragma("unroll")  /* pointwise + inv q=1 in 4-elem register chunks */   \
        for (int s = 0; s < 4; ++s) {                                            \
            int c = n + s * 512;         /* chunk: elements 4c..4c+3 */          \
            float cr0[4], ci0[4];                                                \
            _Pragma("unroll")                                                    \
            for (int e = 0; e < 4; ++e) {                                        \
                int f = 4 * c + e;                                               \
                float2 uv = Ub[f], h0 = Ha[f], h1 = Hb[f];                       \
                float gr = h0.x - h1.y, gi = h0.y + h1.x;  /* h0 + i*h1 */       \
                cr0[e] = uv.x * gr - uv.y * gi;                                  \
                ci0[e] = uv.x * gi + uv.y * gr;                                  \
            }                                                                    \
            float t0r = cr0[0] + cr0[1], t0i = ci0[0] + ci0[1];                  \
            float t2r = cr0[0] - cr0[1], t2i = ci0[0] - ci0[1];                  \
            float t1r = cr0[2] + cr0[3], t1i = ci0[2] + ci0[3];                  \
            float t3r = cr0[2] - cr0[3], t3i = ci0[2] - ci0[3];                  \
            float4 orv = make_float4(t0r + t1r, t2r - t3i, t0r - t1r, t2r + t3i);\
            float4 oiv = make_float4(t0i + t1i, t2i + t3r, t0i - t1i, t2i - t3r);\
            *(float4*)&re[4 * c] = orv;                                          \
            *(float4*)&im[4 * c] = oiv;                                          \
        }                                                                        \
        __syncthreads();                                                         \
        _Pragma("unroll 1")  /* LDS stages q=4,16,64,256,1024 - runtime loop */  \
        for (int st = 2; st <= 10; st += 2) {                                    \
            int q = 1 << st;                                                     \
            int toff = (st == 2) ? 0 : (st == 4) ? 4 : (st == 6) ? 20            \
                     : (st == 8) ? 84 : 340;                                     \
            _Pragma("unroll")                                                    \
            for (int s = 0; s < 4; ++s) {                                        \
                int k = n + s * 512;                                             \
                int j = k & (q - 1);                                             \
                int i0 = ((k >> st) << (st + 2)) + j;                            \
                const float2* tw = t4i + (size_t)(toff + j) * 3;                 \
                float2 W1 = tw[0], W2 = tw[1], W3 = tw[2];                       \
                float Ar = re[i0],       Ai = im[i0];                            \
                float Br = re[i0+q],     Bi = im[i0+q];                          \
                float Cr = re[i0+2*q],   Ci = im[i0+2*q];                        \
                float Dr = re[i0+3*q],   Di = im[i0+3*q];                        \
                float bpr = Br*W2.x - Bi*W2.y, bpi = Br*W2.y + Bi*W2.x;          \
                float cpr = Cr*W1.x - Ci*W1.y, cpi = Cr*W1.y + Ci*W1.x;          \
                float dpr = Dr*W3.x - Di*W3.y, dpi = Dr*W3.y + Di*W3.x;          \
                float t0r = Ar+bpr, t0i = Ai+bpi, t2r = Ar-bpr, t2i = Ai-bpi;    \
                float t1r = cpr+dpr, t1i = cpi+dpi, t3r = cpr-dpr, t3i = cpi-dpi;\
                re[i0]       = t0r+t1r; im[i0]       = t0i+t1i;                  \
                re[i0+2*q]   = t0r-t1r; im[i0+2*q]   = t0i-t1i;                  \
                re[i0+q]     = t2r-t3i; im[i0+q]     = t2i+t3r;                  \
                re[i0+3*q]   = t2r+t3i; im[i0+3*q]   = t2i-t3r;                  \
            }                                                                    \
            __syncthreads();                                                     \
        }                                                                        \
        _Pragma("unroll")  /* R2-last fused + scale + pack (upper half unused) */\
        for (int s = 0; s < 8; ++s) {                                            \
            int k = n + 512 * s;                                                 \
            float2 W = t2i[k];                                                   \
            float br = re[k + 4096], bi = im[k + 4096];                          \
            float tr = W.x * br - W.y * bi, ti = W.x * bi + W.y * br;            \
            PK[s] = pk2h((re[k] + tr) * inv, (im[k] + ti) * inv);                \
        }                                                                        \
    }

    CONV_FF(0, pk0)
    CONV_FF(1, pk1)
    CONV_FF(2, pk2)
    CONV_FF(3, pk3)
#undef CONV_FF

    _Float16* dst = m2 + ((size_t)qb * BT + (size_t)b * T) * 8;
#pragma unroll
    for (int s = 0; s < 8; ++s) {
        int tt = n + 512 * s;
        uint4 w4;
        w4.x = pk0[s]; w4.y = pk1[s]; w4.z = pk2[s]; w4.w = pk3[s];
        *(uint4*)(dst + (size_t)tt * 8) = w4;
    }
}

// ============================ kernel 4: GEMM (unchanged, verified) ============================
__global__ __launch_bounds__(256) void h_gemm_kernel(const _Float16* __restrict__ xh,
                                                     const _Float16* __restrict__ whfT,
                                                     const _Float16* __restrict__ m2,
                                                     float* __restrict__ out) {
    __shared__ __align__(16) _Float16 As[8][128][8];
    __shared__ __align__(16) _Float16 Bs[8][128][8];
    int bn = blockIdx.x;
    int bm = blockIdx.y;
    int t = threadIdx.x;
    int wv = t >> 6, lane = t & 63;
    int wm = (wv & 1) * 64, wn = (wv >> 1) * 64;
    int ln = lane & 15, kg = lane >> 4;

    f32x4 acc[4][4] = {};
#pragma unroll
    for (int ks = 0; ks < 8; ++ks) {
        int kc = ks * 64;
        __syncthreads();
#pragma unroll
        for (int q = 0; q < 8; ++q) {
            int c = wv * 8 + q;
            int g = (c & 15) >> 1;
            int rg = c & 1;
            int row = rg * 64 + lane;
            if (c < 16) {
                const void* src;
                if (kc < MEM)
                    src = m2 + ((size_t)(kc / 8 + g) * BT + (size_t)bm * 128 + row) * 8;
                else
                    src = xh + (size_t)(bm * 128 + row) * IND + (kc - MEM) + g * 8;
                gl_lds16(src, &As[g][rg * 64][0]);
            } else {
                const void* src = whfT + (size_t)(kc / 8 + g) * (HID * 8)
                                       + (size_t)(bn * 128 + row) * 8;
                gl_lds16(src, &Bs[g][rg * 64][0]);
            }
        }
        __syncthreads();
        half8 af[2][4], bf[2][4];
#pragma unroll
        for (int kk = 0; kk < 2; ++kk) {
#pragma unroll
            for (int i = 0; i < 4; ++i)
                af[kk][i] = *(const half8*)&As[kk * 4 + kg][wm + i * 16 + ln][0];
#pragma unroll
            for (int j = 0; j < 4; ++j)
                bf[kk][j] = *(const half8*)&Bs[kk * 4 + kg][wn + j * 16 + ln][0];
        }
#pragma unroll
        for (int kk = 0; kk < 2; ++kk)
#pragma unroll
            for (int i = 0; i < 4; ++i)
#pragma unroll
                for (int j = 0; j < 4; ++j)
                    acc[i][j] = __builtin_amdgcn_mfma_f32_16x16x32_f16(af[kk][i], bf[kk][j],
                                                                       acc[i][j], 0, 0, 0);
    }
#pragma unroll
    for (int i = 0; i < 4; ++i) {
#pragma unroll
        for (int j = 0; j < 4; ++j) {
#pragma unroll
            for (int r = 0; r < 4; ++r) {
                int row = bm * 128 + wm + i * 16 + kg * 4 + r;
                int col = bn * 128 + wn + j * 16 + ln;
                float v = fmaxf(acc[i][j][r], 0.f);
                out[(size_t)row * HID + col] = v;
                if ((row & (T - 1)) == (T - 1))
                    out[(size_t)BATCH * T * HID + (size_t)(row >> 12) * HID + col] = v;
            }
        }
    }
}

// ================== OLD PATH (verbatim fallback, small ws) ==================
__device__ void fft_dif_fwd(float* re, float* im) {
    __syncthreads();
    for (int st = FFT_LOG; st >= 1; --st) {
        int half = 1 << (st - 1);
        float fm = -(float)M_PI / (float)half;
        for (int k = threadIdx.x; k < FFT_N / 2; k += 512) {
            int j  = k & (half - 1);
            int i1 = ((k >> (st - 1)) << st) + j;
            int i2 = i1 + half;
            float sn, cs;
            __sincosf(fm * (float)j, &sn, &cs);
            float ar = re[i1], ai = im[i1];
            float br = re[i2], bi = im[i2];
            re[i1] = ar + br; im[i1] = ai + bi;
            float dr = ar - br, di = ai - bi;
            re[i2] = cs * dr - sn * di;
            im[i2] = cs * di + sn * dr;
        }
        __syncthreads();
    }
}
__device__ void fft_dit_inv(float* re, float* im) {
    __syncthreads();
    for (int st = 1; st <= FFT_LOG; ++st) {
        int half = 1 << (st - 1);
        float fm = (float)M_PI / (float)half;
        for (int k = threadIdx.x; k < FFT_N / 2; k += 512) {
            int j  = k & (half - 1);
            int i1 = ((k >> (st - 1)) << st) + j;
            int i2 = i1 + half;
            float sn, cs;
            __sincosf(fm * (float)j, &sn, &cs);
            float br = re[i2], bi = im[i2];
            float tr = cs * br - sn * bi;
            float ti = cs * bi + sn * br;
            float ar = re[i1], ai = im[i1];
            re[i1] = ar + tr; im[i1] = ai + ti;
            re[i2] = ar - tr; im[i2] = ai - ti;
        }
        __syncthreads();
    }
}
__global__ __launch_bounds__(512) void fft_u_kernel(const float* __restrict__ u,
                                                    float2* __restrict__ Uf) {
    int b = blockIdx.x;
    __shared__ float re[FFT_N];
    __shared__ float im[FFT_N];
    for (int i = threadIdx.x; i < FFT_N; i += 512) {
        re[i] = i < T ? u[(size_t)b * T + i] : 0.f;
        im[i] = 0.f;
    }
    fft_dif_fwd(re, im);
    for (int i = threadIdx.x; i < FFT_N; i += 512)
        Uf[(size_t)b * FFT_N + i] = make_float2(re[i], im[i]);
}
__global__ __launch_bounds__(512) void g_fft_kernel(const float* __restrict__ Wh,
                                                    const float* __restrict__ H,
                                                    float2* __restrict__ Gf) {
    int o = blockIdx.x;
    __shared__ float re[FFT_N];
    __shared__ float im[FFT_N];
    const float* wrow = Wh + (size_t)o * HID;
    float acc[8];
#pragma unroll
    for (int d = 0; d < 8; ++d) acc[d] = 0.f;
    for (int q = 0; q < 256; ++q) {
        float w = wrow[q];
        const float* hrow = H + (size_t)q * T;
#pragma unroll
        for (int d = 0; d < 8; ++d)
            acc[d] = fmaf(w, hrow[threadIdx.x + d * 512], acc[d]);
    }
#pragma unroll
    for (int d = 0; d < 8; ++d) {
        re[threadIdx.x + d * 512] = acc[d];
        im[threadIdx.x + d * 512] = 0.f;
    }
    for (int i = T + threadIdx.x; i < FFT_N; i += 512) { re[i] = 0.f; im[i] = 0.f; }
    fft_dif_fwd(re, im);
    for (int i = threadIdx.x; i < FFT_N; i += 512)
        Gf[(size_t)o * FFT_N + i] = make_float2(re[i], im[i]);
}
__global__ __launch_bounds__(256) void xw_gemm_kernel(const float* __restrict__ x,
                                                      const float* __restrict__ Wh,
                                                      float* __restrict__ out) {
    __shared__ __align__(16) short Asl[4][128][8];
    __shared__ __align__(16) short Bsl[4][128][8];
    int bn = blockIdx.x;
    int bm = blockIdx.y;
    int t = threadIdx.x;
    int wv = t >> 6, lane = t & 63;
    int wm = (wv & 1) * 64, wn = (wv >> 1) * 64;
    int ln = lane & 15, kg = lane >> 4;
    f32x4 acc[4][4] = {};
    int mrow = t >> 1, khalf = t & 1;
    for (int kc = 0; kc < IND; kc += 32) {
        {
            const float* xr = x + ((size_t)(bm * 128 + mrow)) * IND + kc + khalf * 16;
            float4 v0 = *(const float4*)(xr + 0);
            float4 v1 = *(const float4*)(xr + 4);
            float4 v2 = *(const float4*)(xr + 8);
            float4 v3 = *(const float4*)(xr + 12);
            short8 s0 = { f2bf(v0.x), f2bf(v0.y), f2bf(v0.z), f2bf(v0.w),
                          f2bf(v1.x), f2bf(v1.y), f2bf(v1.z), f2bf(v1.w) };
            short8 s1 = { f2bf(v2.x), f2bf(v2.y), f2bf(v2.z), f2bf(v2.w),
                          f2bf(v3.x), f2bf(v3.y), f2bf(v3.z), f2bf(v3.w) };
            const float* wr = Wh + ((size_t)(bn * 128 + mrow)) * HID + 256 + kc + khalf * 16;
            float4 w0 = *(const float4*)(wr + 0);
            float4 w1 = *(const float4*)(wr + 4);
            float4 w2 = *(const float4*)(wr + 8);
            float4 w3 = *(const float4*)(wr + 12);
            short8 b0 = { f2bf(w0.x), f2bf(w0.y), f2bf(w0.z), f2bf(w0.w),
                          f2bf(w1.x), f2bf(w1.y), f2bf(w1.z), f2bf(w1.w) };
            short8 b1 = { f2bf(w2.x), f2bf(w2.y), f2bf(w2.z), f2bf(w2.w),
                          f2bf(w3.x), f2bf(w3.y), f2bf(w3.z), f2bf(w3.w) };
            __syncthreads();
            *(short8*)&Asl[khalf * 2 + 0][mrow][0] = s0;
            *(short8*)&Asl[khalf * 2 + 1][mrow][0] = s1;
            *(short8*)&Bsl[khalf * 2 + 0][mrow][0] = b0;
            *(short8*)&Bsl[khalf * 2 + 1][mrow][0] = b1;
            __syncthreads();
        }
        short8 af[4], bf[4];
#pragma unroll
        for (int i = 0; i < 4; ++i) af[i] = *(short8*)&Asl[kg][wm + i * 16 + ln][0];
#pragma unroll
        for (int j = 0; j < 4; ++j) bf[j] = *(short8*)&Bsl[kg][wn + j * 16 + ln][0];
#pragma unroll
        for (int i = 0; i < 4; ++i)
#pragma unroll
            for (int j = 0; j < 4; ++j)
                acc[i][j] = __builtin_amdgcn_mfma_f32_16x16x32_bf16(af[i], bf[j], acc[i][j], 0, 0, 0);
    }
#pragma unroll
    for (int i = 0; i < 4; ++i) {
#pragma unroll
        for (int j = 0; j < 4; ++j) {
#pragma unroll
            for (int r = 0; r < 4; ++r) {
                int row = bm * 128 + wm + i * 16 + (lane >> 4) * 4 + r;
                int col = bn * 128 + wn + j * 16 + (lane & 15);
                out[(size_t)row * HID + col] = acc[i][j][r];
            }
        }
    }
}
__global__ __launch_bounds__(512) void conv_apply_kernel(const float2* __restrict__ Uf,
                                                         const float2* __restrict__ Gf,
                                                         float* __restrict__ out) {
    int p = blockIdx.x;
    int b = blockIdx.y;
    __shared__ float re[FFT_N];
    __shared__ float im[FFT_N];
    const float2* Ub = Uf + (size_t)b * FFT_N;
    const float2* G0 = Gf + (size_t)(2 * p) * FFT_N;
    const float2* G1 = Gf + (size_t)(2 * p + 1) * FFT_N;
    for (int f = threadIdx.x; f < FFT_N; f += 512) {
        float2 uv = Ub[f], g0 = G0[f], g1 = G1[f];
        float gr = g0.x - g1.y, gi = g0.y + g1.x;
        re[f] = uv.x * gr - uv.y * gi;
        im[f] = uv.x * gi + uv.y * gr;
    }
    fft_dit_inv(re, im);
    const float inv = 1.0f / (float)FFT_N;
    for (int t = threadIdx.x; t < T; t += 512) {
        size_t idx = ((size_t)(b * T + t)) * HID + 2 * p;
        float2 xw = *(const float2*)(out + idx);
        float v0 = fmaxf(fmaf(re[t], inv, xw.x), 0.f);
        float v1 = fmaxf(fmaf(im[t], inv, xw.y), 0.f);
        *(float2*)(out + idx) = make_float2(v0, v1);
        if (t == T - 1) {
            size_t hn = (size_t)BATCH * T * HID + (size_t)b * HID + 2 * p;
            *(float2*)(out + hn) = make_float2(v0, v1);
        }
    }
}

// ============================== launch ==============================
extern "C" void kernel_launch(void* const* d_in, const int* in_sizes, int n_in,
                              void* d_out, int out_size, void* d_ws, size_t ws_size,
                              hipStream_t stream) {
    const float* x  = (const float*)d_in[0];   // 32*4096*256
    const float* Wu = (const float*)d_in[1];   // 256
    const float* Wh = (const float*)d_in[2];   // 512*512
    const float* H  = (const float*)d_in[3];   // 256*4096
    float* out = (float*)d_out;

    char* ws = (char*)d_ws;

    // new-path workspace layout (bytes)
    const size_t off_u   = 0;                                   // u: 0.5 MB
    const size_t off_t4i = 524288;                              // 32 KB (1364*3 float2 = 32736B)
    const size_t off_t2i = off_t4i + 32768;                     // 32 KB (4096 float2)
    const size_t off_t4f = off_t2i + 32768;                     // 32 KB
    const size_t off_t2f = off_t4f + 32768;                     // 32 KB
    const size_t off_xh  = off_t2f + 32768;                     // xh: 64 MB
    const size_t off_whf = off_xh + 67108864;                   // whfT: 0.5 MB
    const size_t off_U   = off_whf + 524288;                    // Uf: 2 MB
    const size_t off_Hf  = off_U  + 2097152;                    // Hf: 16 MB
    const size_t off_m2  = off_Hf + 16777216;                   // m2: 64 MB
    const size_t need    = off_m2 + (size_t)MEM * BT * 2;       // ~147.1 MB

    if (ws_size >= need) {
        float*     ws_u    = (float*)(ws + off_u);
        float2*    ws_t4i  = (float2*)(ws + off_t4i);
        float2*    ws_t2i  = (float2*)(ws + off_t2i);
        float2*    ws_t4f  = (float2*)(ws + off_t4f);
        float2*    ws_t2f  = (float2*)(ws + off_t2f);
        _Float16*  ws_xh   = (_Float16*)(ws + off_xh);
        _Float16*  ws_whfT = (_Float16*)(ws + off_whf);
        float2*    ws_U    = (float2*)(ws + off_U);
        float2*    ws_Hf   = (float2*)(ws + off_Hf);
        _Float16*  ws_m2   = (_Float16*)(ws + off_m2);

        twiddle_kernel<<<11, 512, 0, stream>>>(ws_t4f, ws_t2f, ws_t4i, ws_t2i);
        wh_pack_kernel<<<HID * HID / 4 / 256, 256, 0, stream>>>(Wh, ws_whfT);
        relu_u_kernel<<<BT / 4, 256, 0, stream>>>(x, Wu, ws_u, ws_xh);
        fwd_all_kernel<<<BATCH + MEM, 512, 0, stream>>>(ws_u, H, ws_t4f, ws_t2f, ws_U, ws_Hf);
        conv_m_kernel<<<dim3(MEM / 8, BATCH), 512, 0, stream>>>(ws_U, ws_Hf, ws_t4i, ws_t2i, ws_m2);
        h_gemm_kernel<<<dim3(HID / 128, BT / 128), 256, 0, stream>>>(ws_xh, ws_whfT, ws_m2, out);
    } else {
        // ---- old verified path (G-fold) ----
        float*  ws_u = (float*)ws;
        float2* ws_U = (float2*)(ws + 524288);
        float2* ws_G = (float2*)(ws + 524288 + 2097152);
        relu_u_only_kernel<<<BT / 4, 256, 0, stream>>>(x, Wu, ws_u);
        fft_u_kernel<<<BATCH, 512, 0, stream>>>(ws_u, ws_U);
        g_fft_kernel<<<HID, 512, 0, stream>>>(Wh, H, ws_G);
        xw_gemm_kernel<<<dim3(HID / 128, BATCH * T / 128), 256, 0, stream>>>(x, Wh, out);
        conv_apply_kernel<<<dim3(HID / 2, BATCH), 512, 0, stream>>>(ws_U, ws_G, out);
    }
}